// Round 5
// baseline (133.583 us; speedup 1.0000x reference)
//
#include <hip/hip_runtime.h>

typedef unsigned short u16;
typedef unsigned int u32;
typedef unsigned long long u64;
typedef __attribute__((ext_vector_type(8))) short short8;
typedef __attribute__((ext_vector_type(4))) float f32x4;

#define T_ 4096
#define QSCALE 0.18033688f   // (1/8) * log2(e): folded into Q at proj time
#define CH 2                 // key-tiles per chunk (proven sweet spot)
#define SBAT 1088            // sum over A of 4*ceil((A+1)/CH)
#define PSTRIDE 36           // P strip row stride in u16 (72 B: 8B-aligned, bank-uniform)

#if __has_builtin(__builtin_amdgcn_exp2f)
#define EXP2F(x) __builtin_amdgcn_exp2f(x)
#else
#define EXP2F(x) exp2f(x)
#endif

__device__ __forceinline__ u16 f2bf(float f) {
    unsigned u = __float_as_uint(f);
    u += 0x7FFFu + ((u >> 16) & 1u);   // RNE to bf16
    return (u16)(u >> 16);
}

// ---------------------------------------------------------------------------
// Kernel 0: W -> WTf in MFMA-B-fragment-contiguous order.
// ---------------------------------------------------------------------------
__global__ __launch_bounds__(256) void wtrans_kernel(
    const float* __restrict__ Wq, const float* __restrict__ Wk,
    const float* __restrict__ Wv, u16* __restrict__ WTf)
{
    const int tid  = blockIdx.x * 256 + threadIdx.x;   // 48*256 = 12288
    const int frag = tid >> 6;                          // 0..191
    const int lane = tid & 63;
    const int ng   = frag >> 4;
    const int kc   = frag & 15;
    const int m    = ng >> 2;
    const float* W = (m == 0) ? Wq : (m == 1) ? Wk : Wv;
    const int h  = (ng & 3) * 16 + (lane & 15);
    const int c0 = kc * 32 + (lane >> 4) * 8;
    short8 v;
    #pragma unroll
    for (int j = 0; j < 8; ++j)
        v[j] = (short)f2bf(W[(c0 + j) * 64 + h]);
    *(short8*)(WTf + (size_t)frag * 512 + lane * 8) = v;
}

// ---------------------------------------------------------------------------
// Kernel 1: projection. (Unchanged.)
// ---------------------------------------------------------------------------
__global__ __launch_bounds__(256) void proj_kernel(
    const float* __restrict__ x, const u16* __restrict__ WTf,
    u16* __restrict__ Qf, u16* __restrict__ Kf, u16* __restrict__ Vf)
{
    __shared__ u16 xs[16 * 520];
    __shared__ u16 img[3072];   // Q @0, K @1024, V @2048 (u16 units)
    const int t    = threadIdx.x;
    const int lane = t & 63;
    const int w    = t >> 6;
    const int l16  = lane & 15;
    const int quad = lane >> 4;
    const int rowbase = blockIdx.x * 16;
    const int bat  = rowbase >> 12;
    const int tloc = rowbase & 4095;

    #pragma unroll
    for (int it = 0; it < 8; ++it) {
        int f   = t + it * 256;                 // float4 index, coalesced
        int row = f >> 7;
        int c4  = (f & 127) * 4;
        f32x4 a = *(const f32x4*)(x + (size_t)(rowbase + row) * 512 + c4);
        unsigned lo = (unsigned)f2bf(a[0]) | ((unsigned)f2bf(a[1]) << 16);
        unsigned hi = (unsigned)f2bf(a[2]) | ((unsigned)f2bf(a[3]) << 16);
        *(uint2*)(xs + row * 520 + c4) = make_uint2(lo, hi);
    }
    __syncthreads();

    f32x4 acc[3];
    #pragma unroll
    for (int nt = 0; nt < 3; ++nt) acc[nt] = (f32x4){0.f, 0.f, 0.f, 0.f};

    const u16* ab = xs + l16 * 520 + quad * 8;
    const u16* wb = WTf + (size_t)(w * 3 * 16) * 512 + lane * 8;

    #pragma unroll 4
    for (int kc = 0; kc < 16; ++kc) {
        short8 af = *(const short8*)(ab + kc * 32);
        #pragma unroll
        for (int nt = 0; nt < 3; ++nt) {
            short8 bf = *(const short8*)(wb + (size_t)(nt * 16 + kc) * 512);
            acc[nt] = __builtin_amdgcn_mfma_f32_16x16x32_bf16(af, bf, acc[nt], 0, 0, 0);
        }
    }

    // ---- epilogue: scatter into LDS image ----
    #pragma unroll
    for (int nt = 0; nt < 3; ++nt) {
        int ng = w * 3 + nt;
        if (ng < 8) {
            int ng4  = ng & 3;
            float sc = (ng < 4) ? QSCALE : 1.0f;
            u16* ib  = img + ((ng < 4) ? 0 : 1024) + (ng4 >> 1) * 512
                          + ((ng4 & 1) * 2 + (l16 >> 3)) * 128 + (l16 & 7);
            #pragma unroll
            for (int i = 0; i < 4; ++i)
                ib[(quad * 4 + i) * 8] = f2bf(acc[nt][i] * sc);
        } else {
            int nt2  = ng - 8;
            unsigned lo = (unsigned)f2bf(acc[nt][0]) | ((unsigned)f2bf(acc[nt][1]) << 16);
            unsigned hi = (unsigned)f2bf(acc[nt][2]) | ((unsigned)f2bf(acc[nt][3]) << 16);
            *(uint2*)(img + 2048 + nt2 * 256 + (quad >> 1) * 128 + l16 * 8
                          + (quad & 1) * 4) = make_uint2(lo, hi);
        }
    }
    __syncthreads();

    // ---- coalesced copy-out ----
    const int tb   = tloc >> 4;
    const int kt   = tloc >> 7;
    const int ks   = (tloc >> 5) & 3;
    const int half = (tloc >> 4) & 1;
    uint2 vq = *(uint2*)(img + t * 4);
    uint2 vk = *(uint2*)(img + 1024 + t * 4);
    uint2 vv = *(uint2*)(img + 2048 + t * 4);
    *(uint2*)(Qf + (size_t)(bat * 256 + tb) * 1024 + t * 4) = vq;
    *(uint2*)(Kf + (size_t)(bat * 256 + tb) * 1024 + t * 4) = vk;
    const int nt2c = t >> 6;
    *(uint2*)(Vf + (size_t)((bat * 32 + kt) * 4 + ks) * 2048
                 + nt2c * 512 + half * 256 + (t & 63) * 4) = vv;
}

// ---------------------------------------------------------------------------
// Kernel 2: attention. (Unchanged — launched TWICE as a pure calibration
// probe: the kernel is deterministic and fully overwrites its outputs, so
// re-execution is bit-idempotent. Total-time delta vs round 3's 117.98 µs
// equals attn's standalone duration.)
// ---------------------------------------------------------------------------
__global__ __launch_bounds__(256, 4) void attn_kernel(
    const u16* __restrict__ Qf, const u16* __restrict__ Kf,
    const u16* __restrict__ Vf, u32* __restrict__ pnum,
    float* __restrict__ pden, float* __restrict__ out)
{
    __shared__ u16 Ps[4][2][16 * PSTRIDE];   // [wave][g][q*PSTRIDE + s], 9.2 KB

    const int w    = threadIdx.x >> 6;
    const int lane = threadIdx.x & 63;
    const int l16  = lane & 15;
    const int qd   = lane >> 4;
    const int xcd  = blockIdx.x & 7;
    const int bat  = xcd >> 1;
    const int tw   = ((blockIdx.x >> 3) * 2 + (xcd & 1)) * 4 + w;  // 0..SBAT-1

    int A = 31, pre = 0, cc = 1;
    for (;;) {                               // big-A first
        cc = (A + CH) / CH;
        int cnt4 = 4 * cc;
        if (tw < pre + cnt4) break;
        pre += cnt4; --A;
    }
    const int r    = tw - pre;
    const int c    = r >> 2;                 // my chunk (shared by 4 waves)
    const int b_   = r & 3;
    const int nkt  = A + 1;
    const int q32  = 4 * A + b_;
    const int kt0  = c * CH;
    const int kt1  = min(kt0 + CH, nkt);
    const int slot = bat * SBAT + pre + b_ + 4 * c;   // chunk stride 4

    short8 aq[2][2];
    #pragma unroll
    for (int g = 0; g < 2; ++g)
        #pragma unroll
        for (int f = 0; f < 2; ++f)
            aq[g][f] = *(const short8*)(Qf
                + ((size_t)((bat * 256 + q32 * 2 + g) * 2 + f)) * 512 + lane * 8);

    // constant-ones A-fragment for the den MFMA (bf16 1.0 = 0x3F80)
    short8 ones;
    #pragma unroll
    for (int j = 0; j < 8; ++j) ones[j] = (short)0x3F80;

    f32x4 acc[2][4];
    f32x4 accden[2];
    #pragma unroll
    for (int g = 0; g < 2; ++g) {
        accden[g] = (f32x4){0.f, 0.f, 0.f, 0.f};
        for (int n = 0; n < 4; ++n) acc[g][n] = (f32x4){0.f, 0.f, 0.f, 0.f};
    }

    // per-wave P strip base pointers (row q = l16, col s; u64-aligned writes)
    u16* Pw[2] = { &Ps[w][0][0], &Ps[w][1][0] };

    auto body = [&](int kt) __attribute__((always_inline)) {
        const u16* kfb = Kf + ((size_t)(bat * 256 + kt * 8) * 2) * 512 + lane * 8;
        const u16* vfb = Vf + ((size_t)((bat * 32 + kt) * 16)) * 512 + lane * 8;
        #pragma unroll
        for (int ks = 0; ks < 4; ++ks) {
            // ---- S^T = K*Q^T -> exp -> pack -> LDS strip (write phase) ----
            #pragma unroll
            for (int b = 0; b < 2; ++b) {
                int nt = 2 * ks + b;
                short8 k0 = *(const short8*)(kfb + (size_t)nt * 1024);
                short8 k1 = *(const short8*)(kfb + (size_t)nt * 1024 + 512);
                #pragma unroll
                for (int g = 0; g < 2; ++g) {
                    f32x4 st = (f32x4){0.f, 0.f, 0.f, 0.f};
                    st = __builtin_amdgcn_mfma_f32_16x16x32_bf16(k0, aq[g][0], st, 0, 0, 0);
                    st = __builtin_amdgcn_mfma_f32_16x16x32_bf16(k1, aq[g][1], st, 0, 0, 0);
                    float p0 = EXP2F(st[0]);   // Q pre-scaled: exp2 direct
                    float p1 = EXP2F(st[1]);
                    float p2 = EXP2F(st[2]);
                    float p3 = EXP2F(st[3]);
                    u32 q01 = __builtin_amdgcn_perm(__float_as_uint(p1), __float_as_uint(p0), 0x07060302u);
                    u32 q23 = __builtin_amdgcn_perm(__float_as_uint(p3), __float_as_uint(p2), 0x07060302u);
                    // strip[g][q=l16][s = b*16 + qd*4 .. +4] <- p0..p3 (trunc bf16)
                    u64 pv = (u64)q01 | ((u64)q23 << 32);
                    *(u64*)(Pw[g] + l16 * PSTRIDE + b * 16 + qd * 4) = pv;
                }
            }
            // ---- P^T B-frags from strip (read phase; same-wave, in-order DS) ----
            short8 ap[2];
            #pragma unroll
            for (int g = 0; g < 2; ++g)
                ap[g] = *(const short8*)(Pw[g] + l16 * PSTRIDE + qd * 8);
            // ---- den on the MFMA pipe: D[m][q] = sum_k P^T[k][q] ----
            accden[0] = __builtin_amdgcn_mfma_f32_16x16x32_bf16(ones, ap[0], accden[0], 0, 0, 0);
            accden[1] = __builtin_amdgcn_mfma_f32_16x16x32_bf16(ones, ap[1], accden[1], 0, 0, 0);
            // ---- O^T += V^T * P^T ----
            #pragma unroll
            for (int nt2 = 0; nt2 < 4; ++nt2) {
                short8 av = *(const short8*)(vfb + (size_t)(ks * 4 + nt2) * 512);
                acc[0][nt2] = __builtin_amdgcn_mfma_f32_16x16x32_bf16(av, ap[0], acc[0][nt2], 0, 0, 0);
                acc[1][nt2] = __builtin_amdgcn_mfma_f32_16x16x32_bf16(av, ap[1], acc[1][nt2], 0, 0, 0);
            }
        }
    };

    // straight-line the <=2 key-tile iterations (no dynamic loop)
    body(kt0);
    if (kt0 + 1 < kt1) body(kt0 + 1);

    // den is replicated across rows by the ones-MFMA: lane-local, no reduce
    float den[2] = { accden[0][0], accden[1][0] };

    if (cc == 1) {
        // single chunk: finalize directly (sole writer of these rows)
        const float rd0 = 1.0f / den[0];
        const float rd1 = 1.0f / den[1];
        float* op = out + ((size_t)(bat * T_ + q32 * 32 + l16)) * 64 + qd * 4;
        #pragma unroll
        for (int g = 0; g < 2; ++g) {
            const float rd = g ? rd1 : rd0;
            #pragma unroll
            for (int nt2 = 0; nt2 < 4; ++nt2) {
                f32x4 v;
                #pragma unroll
                for (int i = 0; i < 4; ++i) v[i] = acc[g][nt2][i] * rd;
                *(f32x4*)(op + (size_t)g * 16 * 64 + nt2 * 16) = v;
            }
        }
    } else {
        // flush: dense nt u64 stores to deterministic slot
        u32* np = pnum + (size_t)slot * 1024;
        #pragma unroll
        for (int g = 0; g < 2; ++g)
            #pragma unroll
            for (int nt2 = 0; nt2 < 4; ++nt2) {
                u32 lo = (u32)f2bf(acc[g][nt2][0]) | ((u32)f2bf(acc[g][nt2][1]) << 16);
                u32 hi = (u32)f2bf(acc[g][nt2][2]) | ((u32)f2bf(acc[g][nt2][3]) << 16);
                u64 val = (u64)lo | ((u64)hi << 32);
                __builtin_nontemporal_store(val, (u64*)(np + (g * 4 + nt2) * 128 + lane * 2));
            }
        if (lane < 32)
            __builtin_nontemporal_store(den[lane >> 4],
                                        &pden[(size_t)slot * 32 + lane]);
    }
}

// ---------------------------------------------------------------------------
// Kernel 3: finalize (round-3 reworked version, unchanged).
// ---------------------------------------------------------------------------
__global__ __launch_bounds__(256) void fin_kernel(
    const u32* __restrict__ pnum, const float* __restrict__ pden,
    float* __restrict__ out)
{
    __shared__ float sden[8][32];
    __shared__ float rden[32];
    const int blk  = blockIdx.x;           // 0..1023
    const int xcd  = blk & 7;
    const int bat  = xcd >> 1;
    const int rest = blk >> 3;             // 0..127
    const int q32  = (rest & 63) * 2 + (xcd & 1);
    const int hh   = rest >> 6;            // h half: 0 -> h 0..31, 1 -> 32..63
    const int A = q32 >> 2, b = q32 & 3;
    const int cc = (A + CH) / CH;
    if (cc == 1) return;                   // written directly by attn
    int pre = 0;
    for (int j = 31; j > A; --j) pre += 4 * ((j + CH) / CH);
    const int base = bat * SBAT + pre + b;   // chunk ci at base + 4*ci

    // ---- parallel denominator: 8 groups, ci strided by 8 ----
    {
        const int md  = threadIdx.x & 31;
        const int grp = threadIdx.x >> 5;
        float d = 0.f;
        for (int ci = grp; ci < cc; ci += 8)
            d += pden[(size_t)(base + 4 * ci) * 32 + md];
        sden[grp][md] = d;
    }
    __syncthreads();
    if (threadIdx.x < 32) {
        float d = 0.f;
        #pragma unroll
        for (int g2 = 0; g2 < 8; ++g2) d += sden[g2][threadIdx.x];
        rden[threadIdx.x] = 1.0f / d;
    }
    __syncthreads();

    const int m   = threadIdx.x >> 3;       // out row 0..31
    const int g   = m >> 4;
    const int l16 = m & 15;
    const int h0  = hh * 32 + (threadIdx.x & 7) * 4;   // 4 h per thread
    const int nt2 = h0 >> 4;
    const int q0  = (h0 >> 2) & 3;
    const int off = (g * 4 + nt2) * 128 + q0 * 32 + l16 * 2;

    float sv0 = 0.f, sv1 = 0.f, sv2 = 0.f, sv3 = 0.f;
    const u32* sp = pnum + (size_t)base * 1024 + off;
    uint2 cur = *(const uint2*)sp;
    for (int ci = 1; ci < cc; ++ci) {
        uint2 nxt = *(const uint2*)(sp + (size_t)ci * 4096);   // next in flight
        sv0 += __uint_as_float(cur.x << 16);
        sv1 += __uint_as_float(cur.x & 0xFFFF0000u);
        sv2 += __uint_as_float(cur.y << 16);
        sv3 += __uint_as_float(cur.y & 0xFFFF0000u);
        cur = nxt;
    }
    sv0 += __uint_as_float(cur.x << 16);
    sv1 += __uint_as_float(cur.x & 0xFFFF0000u);
    sv2 += __uint_as_float(cur.y << 16);
    sv3 += __uint_as_float(cur.y & 0xFFFF0000u);

    const float rd = rden[m];
    float* op = out + (size_t)(bat * T_ + q32 * 32 + m) * 64 + h0;
    f32x4 r;
    r[0] = sv0 * rd; r[1] = sv1 * rd; r[2] = sv2 * rd; r[3] = sv3 * rd;
    *(f32x4*)op = r;
}

// ---------------------------------------------------------------------------
extern "C" void kernel_launch(void* const* d_in, const int* in_sizes, int n_in,
                              void* d_out, int out_size, void* d_ws, size_t ws_size,
                              hipStream_t stream)
{
    const float* x  = (const float*)d_in[0];
    const float* Wk = (const float*)d_in[1];
    const float* Wq = (const float*)d_in[2];
    const float* Wv = (const float*)d_in[3];
    float* out = (float*)d_out;

    u16* ws  = (u16*)d_ws;
    u16* WTf = ws;                          // 98304 u16 (padded to 131072)
    u16* Qf  = ws + 131072;                 // 1048576 u16 each
    u16* Kf  = Qf + 1048576;
    u16* Vf  = Kf + 1048576;
    u32*   pnum = (u32*)(Vf + 1048576);     // 4*SBAT*1024 u32  (~17.8 MB)
    float* pden = (float*)(pnum + (size_t)4 * SBAT * 1024);   // 4*SBAT*32 f32

    wtrans_kernel<<<48, 256, 0, stream>>>(Wq, Wk, Wv, WTf);
    proj_kernel<<<1024, 256, 0, stream>>>(x, WTf, Qf, Kf, Vf);
    // CALIBRATION: attn launched twice (bit-idempotent). Total-time delta vs
    // round 3 = attn's standalone duration. Remove after attribution.
    attn_kernel<<<SBAT, 256, 0, stream>>>(Qf, Kf, Vf, pnum, pden, out);
    attn_kernel<<<SBAT, 256, 0, stream>>>(Qf, Kf, Vf, pnum, pden, out);
    fin_kernel<<<1024, 256, 0, stream>>>(pnum, pden, out);
}

// Round 6
// 124.421 us; speedup vs baseline: 1.0736x; 1.0736x over previous
//
#include <hip/hip_runtime.h>

typedef unsigned short u16;
typedef unsigned int u32;
typedef unsigned long long u64;
typedef __attribute__((ext_vector_type(8))) short short8;
typedef __attribute__((ext_vector_type(4))) float f32x4;

#define T_ 4096
#define QSCALE 0.18033688f   // (1/8) * log2(e): folded into Q at proj time
#define CH 2                 // key-tiles per chunk (proven sweet spot)
#define SBAT 1088            // sum over A of 4*ceil((A+1)/CH)
#define PSTRIDE 36           // P strip row stride in u16 (72 B: 8B-aligned, bank-uniform)

#if __has_builtin(__builtin_amdgcn_exp2f)
#define EXP2F(x) __builtin_amdgcn_exp2f(x)
#else
#define EXP2F(x) exp2f(x)
#endif

__device__ __forceinline__ u16 f2bf(float f) {
    unsigned u = __float_as_uint(f);
    u += 0x7FFFu + ((u >> 16) & 1u);   // RNE to bf16
    return (u16)(u >> 16);
}

// ---------------------------------------------------------------------------
// Kernel 0: W -> WTf in MFMA-B-fragment-contiguous order.
// ---------------------------------------------------------------------------
__global__ __launch_bounds__(256) void wtrans_kernel(
    const float* __restrict__ Wq, const float* __restrict__ Wk,
    const float* __restrict__ Wv, u16* __restrict__ WTf)
{
    const int tid  = blockIdx.x * 256 + threadIdx.x;   // 48*256 = 12288
    const int frag = tid >> 6;                          // 0..191
    const int lane = tid & 63;
    const int ng   = frag >> 4;
    const int kc   = frag & 15;
    const int m    = ng >> 2;
    const float* W = (m == 0) ? Wq : (m == 1) ? Wk : Wv;
    const int h  = (ng & 3) * 16 + (lane & 15);
    const int c0 = kc * 32 + (lane >> 4) * 8;
    short8 v;
    #pragma unroll
    for (int j = 0; j < 8; ++j)
        v[j] = (short)f2bf(W[(c0 + j) * 64 + h]);
    *(short8*)(WTf + (size_t)frag * 512 + lane * 8) = v;
}

// ---------------------------------------------------------------------------
// Kernel 1: projection. (Unchanged.)
// ---------------------------------------------------------------------------
__global__ __launch_bounds__(256) void proj_kernel(
    const float* __restrict__ x, const u16* __restrict__ WTf,
    u16* __restrict__ Qf, u16* __restrict__ Kf, u16* __restrict__ Vf)
{
    __shared__ u16 xs[16 * 520];
    __shared__ u16 img[3072];   // Q @0, K @1024, V @2048 (u16 units)
    const int t    = threadIdx.x;
    const int lane = t & 63;
    const int w    = t >> 6;
    const int l16  = lane & 15;
    const int quad = lane >> 4;
    const int rowbase = blockIdx.x * 16;
    const int bat  = rowbase >> 12;
    const int tloc = rowbase & 4095;

    #pragma unroll
    for (int it = 0; it < 8; ++it) {
        int f   = t + it * 256;                 // float4 index, coalesced
        int row = f >> 7;
        int c4  = (f & 127) * 4;
        f32x4 a = *(const f32x4*)(x + (size_t)(rowbase + row) * 512 + c4);
        unsigned lo = (unsigned)f2bf(a[0]) | ((unsigned)f2bf(a[1]) << 16);
        unsigned hi = (unsigned)f2bf(a[2]) | ((unsigned)f2bf(a[3]) << 16);
        *(uint2*)(xs + row * 520 + c4) = make_uint2(lo, hi);
    }
    __syncthreads();

    f32x4 acc[3];
    #pragma unroll
    for (int nt = 0; nt < 3; ++nt) acc[nt] = (f32x4){0.f, 0.f, 0.f, 0.f};

    const u16* ab = xs + l16 * 520 + quad * 8;
    const u16* wb = WTf + (size_t)(w * 3 * 16) * 512 + lane * 8;

    #pragma unroll 4
    for (int kc = 0; kc < 16; ++kc) {
        short8 af = *(const short8*)(ab + kc * 32);
        #pragma unroll
        for (int nt = 0; nt < 3; ++nt) {
            short8 bf = *(const short8*)(wb + (size_t)(nt * 16 + kc) * 512);
            acc[nt] = __builtin_amdgcn_mfma_f32_16x16x32_bf16(af, bf, acc[nt], 0, 0, 0);
        }
    }

    // ---- epilogue: scatter into LDS image ----
    #pragma unroll
    for (int nt = 0; nt < 3; ++nt) {
        int ng = w * 3 + nt;
        if (ng < 8) {
            int ng4  = ng & 3;
            float sc = (ng < 4) ? QSCALE : 1.0f;
            u16* ib  = img + ((ng < 4) ? 0 : 1024) + (ng4 >> 1) * 512
                          + ((ng4 & 1) * 2 + (l16 >> 3)) * 128 + (l16 & 7);
            #pragma unroll
            for (int i = 0; i < 4; ++i)
                ib[(quad * 4 + i) * 8] = f2bf(acc[nt][i] * sc);
        } else {
            int nt2  = ng - 8;
            unsigned lo = (unsigned)f2bf(acc[nt][0]) | ((unsigned)f2bf(acc[nt][1]) << 16);
            unsigned hi = (unsigned)f2bf(acc[nt][2]) | ((unsigned)f2bf(acc[nt][3]) << 16);
            *(uint2*)(img + 2048 + nt2 * 256 + (quad >> 1) * 128 + l16 * 8
                          + (quad & 1) * 4) = make_uint2(lo, hi);
        }
    }
    __syncthreads();

    // ---- coalesced copy-out ----
    const int tb   = tloc >> 4;
    const int kt   = tloc >> 7;
    const int ks   = (tloc >> 5) & 3;
    const int half = (tloc >> 4) & 1;
    uint2 vq = *(uint2*)(img + t * 4);
    uint2 vk = *(uint2*)(img + 1024 + t * 4);
    uint2 vv = *(uint2*)(img + 2048 + t * 4);
    *(uint2*)(Qf + (size_t)(bat * 256 + tb) * 1024 + t * 4) = vq;
    *(uint2*)(Kf + (size_t)(bat * 256 + tb) * 1024 + t * 4) = vk;
    const int nt2c = t >> 6;
    *(uint2*)(Vf + (size_t)((bat * 32 + kt) * 4 + ks) * 2048
                 + nt2c * 512 + half * 256 + (t & 63) * 4) = vv;
}

// ---------------------------------------------------------------------------
// Kernel 2: attention — NEW this round: cooperative LDS staging of K/V.
// All 4 waves of a block provably share (bat, A, chunk): block tw-base and
// pre are both multiples of 4, so r0 = tw_base - pre ≡ 0 (mod 4) and the
// waves differ only in b_ (q32). Previously each wave re-read the identical
// K/V tiles from L2 (4x redundant, ~270 MB total). Now: one coalesced
// 256-thread copy of the chunk's K+V tiles (<=64 KB) into LDS, one
// __syncthreads, then all fragment reads come from LDS (layout mirrors
// global, so all offsets are unchanged -> bit-identical arithmetic).
// LDS: 64 KB KV + 9 KB P strips = 73 KB -> 2 blocks/CU.
// ---------------------------------------------------------------------------
__global__ __launch_bounds__(256, 2) void attn_kernel(
    const u16* __restrict__ Qf, const u16* __restrict__ Kf,
    const u16* __restrict__ Vf, u32* __restrict__ pnum,
    float* __restrict__ pden, float* __restrict__ out)
{
    __shared__ u16 KVs[32768];               // K: u16 [0,16384) (2 tiles), V: [16384,32768)
    __shared__ u16 Ps[4][2][16 * PSTRIDE];   // [wave][g][q*PSTRIDE + s], 9.2 KB

    const int w    = threadIdx.x >> 6;
    const int lane = threadIdx.x & 63;
    const int l16  = lane & 15;
    const int qd   = lane >> 4;
    const int xcd  = blockIdx.x & 7;
    const int bat  = xcd >> 1;
    const int tw   = ((blockIdx.x >> 3) * 2 + (xcd & 1)) * 4 + w;  // 0..SBAT-1

    int A = 31, pre = 0, cc = 1;
    for (;;) {                               // big-A first
        cc = (A + CH) / CH;
        int cnt4 = 4 * cc;
        if (tw < pre + cnt4) break;
        pre += cnt4; --A;
    }
    const int r    = tw - pre;
    const int c    = r >> 2;                 // my chunk (shared by all 4 waves)
    const int b_   = r & 3;
    const int nkt  = A + 1;
    const int q32  = 4 * A + b_;
    const int kt0  = c * CH;
    const int kt1  = min(kt0 + CH, nkt);
    const int slot = bat * SBAT + pre + b_ + 4 * c;   // chunk stride 4
    const int tiles = kt1 - kt0;             // 1 or 2, uniform across the block

    short8 aq[2][2];
    #pragma unroll
    for (int g = 0; g < 2; ++g)
        #pragma unroll
        for (int f = 0; f < 2; ++f)
            aq[g][f] = *(const short8*)(Qf
                + ((size_t)((bat * 256 + q32 * 2 + g) * 2 + f)) * 512 + lane * 8);

    // ---- cooperative K/V staging: coalesced 16B/thread copy, LDS mirrors
    // global layout (K tiles contiguous at +16KB, V tiles contiguous) ----
    {
        const short8* gk = (const short8*)(Kf + ((size_t)(bat * 256 + kt0 * 8) * 2) * 512);
        const short8* gv = (const short8*)(Vf + ((size_t)((bat * 32 + kt0) * 16)) * 512);
        short8* lk = (short8*)&KVs[0];
        short8* lv = (short8*)&KVs[16384];
        const int nv = tiles * 1024;         // short8 per array (16KB/tile/16B)
        for (int o = threadIdx.x; o < nv; o += 256) {
            lk[o] = gk[o];
            lv[o] = gv[o];
        }
    }
    __syncthreads();

    // constant-ones A-fragment for the den MFMA (bf16 1.0 = 0x3F80)
    short8 ones;
    #pragma unroll
    for (int j = 0; j < 8; ++j) ones[j] = (short)0x3F80;

    f32x4 acc[2][4];
    f32x4 accden[2];
    #pragma unroll
    for (int g = 0; g < 2; ++g) {
        accden[g] = (f32x4){0.f, 0.f, 0.f, 0.f};
        for (int n = 0; n < 4; ++n) acc[g][n] = (f32x4){0.f, 0.f, 0.f, 0.f};
    }

    // per-wave P strip base pointers (row q = l16, col s; u64-aligned writes)
    u16* Pw[2] = { &Ps[w][0][0], &Ps[w][1][0] };

    auto body = [&](int tt) __attribute__((always_inline)) {
        const u16* kfb = KVs + tt * 8192 + lane * 8;
        const u16* vfb = KVs + 16384 + tt * 8192 + lane * 8;
        #pragma unroll
        for (int ks = 0; ks < 4; ++ks) {
            // ---- S^T = K*Q^T -> exp -> pack -> LDS strip (write phase) ----
            #pragma unroll
            for (int b = 0; b < 2; ++b) {
                int nt = 2 * ks + b;
                short8 k0 = *(const short8*)(kfb + nt * 1024);
                short8 k1 = *(const short8*)(kfb + nt * 1024 + 512);
                #pragma unroll
                for (int g = 0; g < 2; ++g) {
                    f32x4 st = (f32x4){0.f, 0.f, 0.f, 0.f};
                    st = __builtin_amdgcn_mfma_f32_16x16x32_bf16(k0, aq[g][0], st, 0, 0, 0);
                    st = __builtin_amdgcn_mfma_f32_16x16x32_bf16(k1, aq[g][1], st, 0, 0, 0);
                    float p0 = EXP2F(st[0]);   // Q pre-scaled: exp2 direct
                    float p1 = EXP2F(st[1]);
                    float p2 = EXP2F(st[2]);
                    float p3 = EXP2F(st[3]);
                    u32 q01 = __builtin_amdgcn_perm(__float_as_uint(p1), __float_as_uint(p0), 0x07060302u);
                    u32 q23 = __builtin_amdgcn_perm(__float_as_uint(p3), __float_as_uint(p2), 0x07060302u);
                    // strip[g][q=l16][s = b*16 + qd*4 .. +4] <- p0..p3 (trunc bf16)
                    u64 pv = (u64)q01 | ((u64)q23 << 32);
                    *(u64*)(Pw[g] + l16 * PSTRIDE + b * 16 + qd * 4) = pv;
                }
            }
            // ---- P^T B-frags from strip (read phase; same-wave, in-order DS) ----
            short8 ap[2];
            #pragma unroll
            for (int g = 0; g < 2; ++g)
                ap[g] = *(const short8*)(Pw[g] + l16 * PSTRIDE + qd * 8);
            // ---- den on the MFMA pipe: D[m][q] = sum_k P^T[k][q] ----
            accden[0] = __builtin_amdgcn_mfma_f32_16x16x32_bf16(ones, ap[0], accden[0], 0, 0, 0);
            accden[1] = __builtin_amdgcn_mfma_f32_16x16x32_bf16(ones, ap[1], accden[1], 0, 0, 0);
            // ---- O^T += V^T * P^T ----
            #pragma unroll
            for (int nt2 = 0; nt2 < 4; ++nt2) {
                short8 av = *(const short8*)(vfb + (ks * 4 + nt2) * 512);
                acc[0][nt2] = __builtin_amdgcn_mfma_f32_16x16x32_bf16(av, ap[0], acc[0][nt2], 0, 0, 0);
                acc[1][nt2] = __builtin_amdgcn_mfma_f32_16x16x32_bf16(av, ap[1], acc[1][nt2], 0, 0, 0);
            }
        }
    };

    // straight-line the <=2 key-tile iterations (no dynamic loop)
    body(0);
    if (tiles == 2) body(1);

    // den is replicated across rows by the ones-MFMA: lane-local, no reduce
    float den[2] = { accden[0][0], accden[1][0] };

    if (cc == 1) {
        // single chunk: finalize directly (sole writer of these rows)
        const float rd0 = 1.0f / den[0];
        const float rd1 = 1.0f / den[1];
        float* op = out + ((size_t)(bat * T_ + q32 * 32 + l16)) * 64 + qd * 4;
        #pragma unroll
        for (int g = 0; g < 2; ++g) {
            const float rd = g ? rd1 : rd0;
            #pragma unroll
            for (int nt2 = 0; nt2 < 4; ++nt2) {
                f32x4 v;
                #pragma unroll
                for (int i = 0; i < 4; ++i) v[i] = acc[g][nt2][i] * rd;
                *(f32x4*)(op + (size_t)g * 16 * 64 + nt2 * 16) = v;
            }
        }
    } else {
        // flush: dense nt u64 stores to deterministic slot
        u32* np = pnum + (size_t)slot * 1024;
        #pragma unroll
        for (int g = 0; g < 2; ++g)
            #pragma unroll
            for (int nt2 = 0; nt2 < 4; ++nt2) {
                u32 lo = (u32)f2bf(acc[g][nt2][0]) | ((u32)f2bf(acc[g][nt2][1]) << 16);
                u32 hi = (u32)f2bf(acc[g][nt2][2]) | ((u32)f2bf(acc[g][nt2][3]) << 16);
                u64 val = (u64)lo | ((u64)hi << 32);
                __builtin_nontemporal_store(val, (u64*)(np + (g * 4 + nt2) * 128 + lane * 2));
            }
        if (lane < 32)
            __builtin_nontemporal_store(den[lane >> 4],
                                        &pden[(size_t)slot * 32 + lane]);
    }
}

// ---------------------------------------------------------------------------
// Kernel 3: finalize (round-3 reworked version, unchanged).
// ---------------------------------------------------------------------------
__global__ __launch_bounds__(256) void fin_kernel(
    const u32* __restrict__ pnum, const float* __restrict__ pden,
    float* __restrict__ out)
{
    __shared__ float sden[8][32];
    __shared__ float rden[32];
    const int blk  = blockIdx.x;           // 0..1023
    const int xcd  = blk & 7;
    const int bat  = xcd >> 1;
    const int rest = blk >> 3;             // 0..127
    const int q32  = (rest & 63) * 2 + (xcd & 1);
    const int hh   = rest >> 6;            // h half: 0 -> h 0..31, 1 -> 32..63
    const int A = q32 >> 2, b = q32 & 3;
    const int cc = (A + CH) / CH;
    if (cc == 1) return;                   // written directly by attn
    int pre = 0;
    for (int j = 31; j > A; --j) pre += 4 * ((j + CH) / CH);
    const int base = bat * SBAT + pre + b;   // chunk ci at base + 4*ci

    // ---- parallel denominator: 8 groups, ci strided by 8 ----
    {
        const int md  = threadIdx.x & 31;
        const int grp = threadIdx.x >> 5;
        float d = 0.f;
        for (int ci = grp; ci < cc; ci += 8)
            d += pden[(size_t)(base + 4 * ci) * 32 + md];
        sden[grp][md] = d;
    }
    __syncthreads();
    if (threadIdx.x < 32) {
        float d = 0.f;
        #pragma unroll
        for (int g2 = 0; g2 < 8; ++g2) d += sden[g2][threadIdx.x];
        rden[threadIdx.x] = 1.0f / d;
    }
    __syncthreads();

    const int m   = threadIdx.x >> 3;       // out row 0..31
    const int g   = m >> 4;
    const int l16 = m & 15;
    const int h0  = hh * 32 + (threadIdx.x & 7) * 4;   // 4 h per thread
    const int nt2 = h0 >> 4;
    const int q0  = (h0 >> 2) & 3;
    const int off = (g * 4 + nt2) * 128 + q0 * 32 + l16 * 2;

    float sv0 = 0.f, sv1 = 0.f, sv2 = 0.f, sv3 = 0.f;
    const u32* sp = pnum + (size_t)base * 1024 + off;
    uint2 cur = *(const uint2*)sp;
    for (int ci = 1; ci < cc; ++ci) {
        uint2 nxt = *(const uint2*)(sp + (size_t)ci * 4096);   // next in flight
        sv0 += __uint_as_float(cur.x << 16);
        sv1 += __uint_as_float(cur.x & 0xFFFF0000u);
        sv2 += __uint_as_float(cur.y << 16);
        sv3 += __uint_as_float(cur.y & 0xFFFF0000u);
        cur = nxt;
    }
    sv0 += __uint_as_float(cur.x << 16);
    sv1 += __uint_as_float(cur.x & 0xFFFF0000u);
    sv2 += __uint_as_float(cur.y << 16);
    sv3 += __uint_as_float(cur.y & 0xFFFF0000u);

    const float rd = rden[m];
    float* op = out + (size_t)(bat * T_ + q32 * 32 + m) * 64 + h0;
    f32x4 r;
    r[0] = sv0 * rd; r[1] = sv1 * rd; r[2] = sv2 * rd; r[3] = sv3 * rd;
    *(f32x4*)op = r;
}

// ---------------------------------------------------------------------------
extern "C" void kernel_launch(void* const* d_in, const int* in_sizes, int n_in,
                              void* d_out, int out_size, void* d_ws, size_t ws_size,
                              hipStream_t stream)
{
    const float* x  = (const float*)d_in[0];
    const float* Wk = (const float*)d_in[1];
    const float* Wq = (const float*)d_in[2];
    const float* Wv = (const float*)d_in[3];
    float* out = (float*)d_out;

    u16* ws  = (u16*)d_ws;
    u16* WTf = ws;                          // 98304 u16 (padded to 131072)
    u16* Qf  = ws + 131072;                 // 1048576 u16 each
    u16* Kf  = Qf + 1048576;
    u16* Vf  = Kf + 1048576;
    u32*   pnum = (u32*)(Vf + 1048576);     // 4*SBAT*1024 u32  (~17.8 MB)
    float* pden = (float*)(pnum + (size_t)4 * SBAT * 1024);   // 4*SBAT*32 f32

    wtrans_kernel<<<48, 256, 0, stream>>>(Wq, Wk, Wv, WTf);
    proj_kernel<<<1024, 256, 0, stream>>>(x, WTf, Qf, Kf, Vf);
    attn_kernel<<<SBAT, 256, 0, stream>>>(Qf, Kf, Vf, pnum, pden, out);
    fin_kernel<<<1024, 256, 0, stream>>>(pnum, pden, out);
}

// Round 7
// 117.696 us; speedup vs baseline: 1.1350x; 1.0571x over previous
//
#include <hip/hip_runtime.h>

typedef unsigned short u16;
typedef unsigned int u32;
typedef unsigned long long u64;
typedef __attribute__((ext_vector_type(8))) short short8;
typedef __attribute__((ext_vector_type(4))) float f32x4;

#define T_ 4096
#define QSCALE 0.18033688f   // (1/8) * log2(e): folded into Q at proj time
#define CH 4                 // key-tiles per chunk (this round: 2 -> 4)
#define SBAT 576             // sum over A of 4*ceil((A+1)/CH)  [CH=4]
#define PSTRIDE 36           // P strip row stride in u16 (72 B: 8B-aligned, bank-uniform)

#if __has_builtin(__builtin_amdgcn_exp2f)
#define EXP2F(x) __builtin_amdgcn_exp2f(x)
#else
#define EXP2F(x) exp2f(x)
#endif

__device__ __forceinline__ u16 f2bf(float f) {
    unsigned u = __float_as_uint(f);
    u += 0x7FFFu + ((u >> 16) & 1u);   // RNE to bf16
    return (u16)(u >> 16);
}

// ---------------------------------------------------------------------------
// Kernel 0: W -> WTf in MFMA-B-fragment-contiguous order.
// ---------------------------------------------------------------------------
__global__ __launch_bounds__(256) void wtrans_kernel(
    const float* __restrict__ Wq, const float* __restrict__ Wk,
    const float* __restrict__ Wv, u16* __restrict__ WTf)
{
    const int tid  = blockIdx.x * 256 + threadIdx.x;   // 48*256 = 12288
    const int frag = tid >> 6;                          // 0..191
    const int lane = tid & 63;
    const int ng   = frag >> 4;
    const int kc   = frag & 15;
    const int m    = ng >> 2;
    const float* W = (m == 0) ? Wq : (m == 1) ? Wk : Wv;
    const int h  = (ng & 3) * 16 + (lane & 15);
    const int c0 = kc * 32 + (lane >> 4) * 8;
    short8 v;
    #pragma unroll
    for (int j = 0; j < 8; ++j)
        v[j] = (short)f2bf(W[(c0 + j) * 64 + h]);
    *(short8*)(WTf + (size_t)frag * 512 + lane * 8) = v;
}

// ---------------------------------------------------------------------------
// Kernel 1: projection. (Unchanged.)
// ---------------------------------------------------------------------------
__global__ __launch_bounds__(256) void proj_kernel(
    const float* __restrict__ x, const u16* __restrict__ WTf,
    u16* __restrict__ Qf, u16* __restrict__ Kf, u16* __restrict__ Vf)
{
    __shared__ u16 xs[16 * 520];
    __shared__ u16 img[3072];   // Q @0, K @1024, V @2048 (u16 units)
    const int t    = threadIdx.x;
    const int lane = t & 63;
    const int w    = t >> 6;
    const int l16  = lane & 15;
    const int quad = lane >> 4;
    const int rowbase = blockIdx.x * 16;
    const int bat  = rowbase >> 12;
    const int tloc = rowbase & 4095;

    #pragma unroll
    for (int it = 0; it < 8; ++it) {
        int f   = t + it * 256;                 // float4 index, coalesced
        int row = f >> 7;
        int c4  = (f & 127) * 4;
        f32x4 a = *(const f32x4*)(x + (size_t)(rowbase + row) * 512 + c4);
        unsigned lo = (unsigned)f2bf(a[0]) | ((unsigned)f2bf(a[1]) << 16);
        unsigned hi = (unsigned)f2bf(a[2]) | ((unsigned)f2bf(a[3]) << 16);
        *(uint2*)(xs + row * 520 + c4) = make_uint2(lo, hi);
    }
    __syncthreads();

    f32x4 acc[3];
    #pragma unroll
    for (int nt = 0; nt < 3; ++nt) acc[nt] = (f32x4){0.f, 0.f, 0.f, 0.f};

    const u16* ab = xs + l16 * 520 + quad * 8;
    const u16* wb = WTf + (size_t)(w * 3 * 16) * 512 + lane * 8;

    #pragma unroll 4
    for (int kc = 0; kc < 16; ++kc) {
        short8 af = *(const short8*)(ab + kc * 32);
        #pragma unroll
        for (int nt = 0; nt < 3; ++nt) {
            short8 bf = *(const short8*)(wb + (size_t)(nt * 16 + kc) * 512);
            acc[nt] = __builtin_amdgcn_mfma_f32_16x16x32_bf16(af, bf, acc[nt], 0, 0, 0);
        }
    }

    // ---- epilogue: scatter into LDS image ----
    #pragma unroll
    for (int nt = 0; nt < 3; ++nt) {
        int ng = w * 3 + nt;
        if (ng < 8) {
            int ng4  = ng & 3;
            float sc = (ng < 4) ? QSCALE : 1.0f;
            u16* ib  = img + ((ng < 4) ? 0 : 1024) + (ng4 >> 1) * 512
                          + ((ng4 & 1) * 2 + (l16 >> 3)) * 128 + (l16 & 7);
            #pragma unroll
            for (int i = 0; i < 4; ++i)
                ib[(quad * 4 + i) * 8] = f2bf(acc[nt][i] * sc);
        } else {
            int nt2  = ng - 8;
            unsigned lo = (unsigned)f2bf(acc[nt][0]) | ((unsigned)f2bf(acc[nt][1]) << 16);
            unsigned hi = (unsigned)f2bf(acc[nt][2]) | ((unsigned)f2bf(acc[nt][3]) << 16);
            *(uint2*)(img + 2048 + nt2 * 256 + (quad >> 1) * 128 + l16 * 8
                          + (quad & 1) * 4) = make_uint2(lo, hi);
        }
    }
    __syncthreads();

    // ---- coalesced copy-out ----
    const int tb   = tloc >> 4;
    const int kt   = tloc >> 7;
    const int ks   = (tloc >> 5) & 3;
    const int half = (tloc >> 4) & 1;
    uint2 vq = *(uint2*)(img + t * 4);
    uint2 vk = *(uint2*)(img + 1024 + t * 4);
    uint2 vv = *(uint2*)(img + 2048 + t * 4);
    *(uint2*)(Qf + (size_t)(bat * 256 + tb) * 1024 + t * 4) = vq;
    *(uint2*)(Kf + (size_t)(bat * 256 + tb) * 1024 + t * 4) = vk;
    const int nt2c = t >> 6;
    *(uint2*)(Vf + (size_t)((bat * 32 + kt) * 4 + ks) * 2048
                 + nt2c * 512 + half * 256 + (t & 63) * 4) = vv;
}

// ---------------------------------------------------------------------------
// Kernel 2: attention — round-3 structure REVERTED (direct L2 K/V reads,
// barrier-free, 4 blocks/CU; the round-6 LDS staging regressed: attn is
// latency-bound, occupancy matters more than K/V traffic). CH=2 -> 4:
// half the waves (SBAT 1088 -> 576, one resident dispatch round), Q-load +
// decode + flush amortized over 2x tiles, pnum partial traffic halved.
// Up to 4 straight-lined tile bodies.
// ---------------------------------------------------------------------------
__global__ __launch_bounds__(256, 4) void attn_kernel(
    const u16* __restrict__ Qf, const u16* __restrict__ Kf,
    const u16* __restrict__ Vf, u32* __restrict__ pnum,
    float* __restrict__ pden, float* __restrict__ out)
{
    __shared__ u16 Ps[4][2][16 * PSTRIDE];   // [wave][g][q*PSTRIDE + s], 9.2 KB

    const int w    = threadIdx.x >> 6;
    const int lane = threadIdx.x & 63;
    const int l16  = lane & 15;
    const int qd   = lane >> 4;
    const int xcd  = blockIdx.x & 7;
    const int bat  = xcd >> 1;
    const int tw   = ((blockIdx.x >> 3) * 2 + (xcd & 1)) * 4 + w;  // 0..SBAT-1

    int A = 31, pre = 0, cc = 1;
    for (;;) {                               // big-A first
        cc = (A + CH) / CH;
        int cnt4 = 4 * cc;
        if (tw < pre + cnt4) break;
        pre += cnt4; --A;
    }
    const int r    = tw - pre;
    const int c    = r >> 2;                 // my chunk (shared by 4 waves)
    const int b_   = r & 3;
    const int nkt  = A + 1;
    const int q32  = 4 * A + b_;
    const int kt0  = c * CH;
    const int kt1  = min(kt0 + CH, nkt);
    const int slot = bat * SBAT + pre + b_ + 4 * c;   // chunk stride 4

    short8 aq[2][2];
    #pragma unroll
    for (int g = 0; g < 2; ++g)
        #pragma unroll
        for (int f = 0; f < 2; ++f)
            aq[g][f] = *(const short8*)(Qf
                + ((size_t)((bat * 256 + q32 * 2 + g) * 2 + f)) * 512 + lane * 8);

    // constant-ones A-fragment for the den MFMA (bf16 1.0 = 0x3F80)
    short8 ones;
    #pragma unroll
    for (int j = 0; j < 8; ++j) ones[j] = (short)0x3F80;

    f32x4 acc[2][4];
    f32x4 accden[2];
    #pragma unroll
    for (int g = 0; g < 2; ++g) {
        accden[g] = (f32x4){0.f, 0.f, 0.f, 0.f};
        for (int n = 0; n < 4; ++n) acc[g][n] = (f32x4){0.f, 0.f, 0.f, 0.f};
    }

    // per-wave P strip base pointers (row q = l16, col s; u64-aligned writes)
    u16* Pw[2] = { &Ps[w][0][0], &Ps[w][1][0] };

    auto body = [&](int kt) __attribute__((always_inline)) {
        const u16* kfb = Kf + ((size_t)(bat * 256 + kt * 8) * 2) * 512 + lane * 8;
        const u16* vfb = Vf + ((size_t)((bat * 32 + kt) * 16)) * 512 + lane * 8;
        #pragma unroll
        for (int ks = 0; ks < 4; ++ks) {
            // ---- S^T = K*Q^T -> exp -> pack -> LDS strip (write phase) ----
            #pragma unroll
            for (int b = 0; b < 2; ++b) {
                int nt = 2 * ks + b;
                short8 k0 = *(const short8*)(kfb + (size_t)nt * 1024);
                short8 k1 = *(const short8*)(kfb + (size_t)nt * 1024 + 512);
                #pragma unroll
                for (int g = 0; g < 2; ++g) {
                    f32x4 st = (f32x4){0.f, 0.f, 0.f, 0.f};
                    st = __builtin_amdgcn_mfma_f32_16x16x32_bf16(k0, aq[g][0], st, 0, 0, 0);
                    st = __builtin_amdgcn_mfma_f32_16x16x32_bf16(k1, aq[g][1], st, 0, 0, 0);
                    float p0 = EXP2F(st[0]);   // Q pre-scaled: exp2 direct
                    float p1 = EXP2F(st[1]);
                    float p2 = EXP2F(st[2]);
                    float p3 = EXP2F(st[3]);
                    u32 q01 = __builtin_amdgcn_perm(__float_as_uint(p1), __float_as_uint(p0), 0x07060302u);
                    u32 q23 = __builtin_amdgcn_perm(__float_as_uint(p3), __float_as_uint(p2), 0x07060302u);
                    // strip[g][q=l16][s = b*16 + qd*4 .. +4] <- p0..p3 (trunc bf16)
                    u64 pv = (u64)q01 | ((u64)q23 << 32);
                    *(u64*)(Pw[g] + l16 * PSTRIDE + b * 16 + qd * 4) = pv;
                }
            }
            // ---- P^T B-frags from strip (read phase; same-wave, in-order DS) ----
            short8 ap[2];
            #pragma unroll
            for (int g = 0; g < 2; ++g)
                ap[g] = *(const short8*)(Pw[g] + l16 * PSTRIDE + qd * 8);
            // ---- den on the MFMA pipe: D[m][q] = sum_k P^T[k][q] ----
            accden[0] = __builtin_amdgcn_mfma_f32_16x16x32_bf16(ones, ap[0], accden[0], 0, 0, 0);
            accden[1] = __builtin_amdgcn_mfma_f32_16x16x32_bf16(ones, ap[1], accden[1], 0, 0, 0);
            // ---- O^T += V^T * P^T ----
            #pragma unroll
            for (int nt2 = 0; nt2 < 4; ++nt2) {
                short8 av = *(const short8*)(vfb + (size_t)(ks * 4 + nt2) * 512);
                acc[0][nt2] = __builtin_amdgcn_mfma_f32_16x16x32_bf16(av, ap[0], acc[0][nt2], 0, 0, 0);
                acc[1][nt2] = __builtin_amdgcn_mfma_f32_16x16x32_bf16(av, ap[1], acc[1][nt2], 0, 0, 0);
            }
        }
    };

    // straight-line the <=4 key-tile iterations (no dynamic loop)
    body(kt0);
    if (kt0 + 1 < kt1) body(kt0 + 1);
    if (kt0 + 2 < kt1) body(kt0 + 2);
    if (kt0 + 3 < kt1) body(kt0 + 3);

    // den is replicated across rows by the ones-MFMA: lane-local, no reduce
    float den[2] = { accden[0][0], accden[1][0] };

    if (cc == 1) {
        // single chunk: finalize directly (sole writer of these rows)
        const float rd0 = 1.0f / den[0];
        const float rd1 = 1.0f / den[1];
        float* op = out + ((size_t)(bat * T_ + q32 * 32 + l16)) * 64 + qd * 4;
        #pragma unroll
        for (int g = 0; g < 2; ++g) {
            const float rd = g ? rd1 : rd0;
            #pragma unroll
            for (int nt2 = 0; nt2 < 4; ++nt2) {
                f32x4 v;
                #pragma unroll
                for (int i = 0; i < 4; ++i) v[i] = acc[g][nt2][i] * rd;
                *(f32x4*)(op + (size_t)g * 16 * 64 + nt2 * 16) = v;
            }
        }
    } else {
        // flush: dense nt u64 stores to deterministic slot
        u32* np = pnum + (size_t)slot * 1024;
        #pragma unroll
        for (int g = 0; g < 2; ++g)
            #pragma unroll
            for (int nt2 = 0; nt2 < 4; ++nt2) {
                u32 lo = (u32)f2bf(acc[g][nt2][0]) | ((u32)f2bf(acc[g][nt2][1]) << 16);
                u32 hi = (u32)f2bf(acc[g][nt2][2]) | ((u32)f2bf(acc[g][nt2][3]) << 16);
                u64 val = (u64)lo | ((u64)hi << 32);
                __builtin_nontemporal_store(val, (u64*)(np + (g * 4 + nt2) * 128 + lane * 2));
            }
        if (lane < 32)
            __builtin_nontemporal_store(den[lane >> 4],
                                        &pden[(size_t)slot * 32 + lane]);
    }
}

// ---------------------------------------------------------------------------
// Kernel 3: finalize (round-3 reworked version; adapts to CH via macros).
// ---------------------------------------------------------------------------
__global__ __launch_bounds__(256) void fin_kernel(
    const u32* __restrict__ pnum, const float* __restrict__ pden,
    float* __restrict__ out)
{
    __shared__ float sden[8][32];
    __shared__ float rden[32];
    const int blk  = blockIdx.x;           // 0..1023
    const int xcd  = blk & 7;
    const int bat  = xcd >> 1;
    const int rest = blk >> 3;             // 0..127
    const int q32  = (rest & 63) * 2 + (xcd & 1);
    const int hh   = rest >> 6;            // h half: 0 -> h 0..31, 1 -> 32..63
    const int A = q32 >> 2, b = q32 & 3;
    const int cc = (A + CH) / CH;
    if (cc == 1) return;                   // written directly by attn
    int pre = 0;
    for (int j = 31; j > A; --j) pre += 4 * ((j + CH) / CH);
    const int base = bat * SBAT + pre + b;   // chunk ci at base + 4*ci

    // ---- parallel denominator: 8 groups, ci strided by 8 ----
    {
        const int md  = threadIdx.x & 31;
        const int grp = threadIdx.x >> 5;
        float d = 0.f;
        for (int ci = grp; ci < cc; ci += 8)
            d += pden[(size_t)(base + 4 * ci) * 32 + md];
        sden[grp][md] = d;
    }
    __syncthreads();
    if (threadIdx.x < 32) {
        float d = 0.f;
        #pragma unroll
        for (int g2 = 0; g2 < 8; ++g2) d += sden[g2][threadIdx.x];
        rden[threadIdx.x] = 1.0f / d;
    }
    __syncthreads();

    const int m   = threadIdx.x >> 3;       // out row 0..31
    const int g   = m >> 4;
    const int l16 = m & 15;
    const int h0  = hh * 32 + (threadIdx.x & 7) * 4;   // 4 h per thread
    const int nt2 = h0 >> 4;
    const int q0  = (h0 >> 2) & 3;
    const int off = (g * 4 + nt2) * 128 + q0 * 32 + l16 * 2;

    float sv0 = 0.f, sv1 = 0.f, sv2 = 0.f, sv3 = 0.f;
    const u32* sp = pnum + (size_t)base * 1024 + off;
    uint2 cur = *(const uint2*)sp;
    for (int ci = 1; ci < cc; ++ci) {
        uint2 nxt = *(const uint2*)(sp + (size_t)ci * 4096);   // next in flight
        sv0 += __uint_as_float(cur.x << 16);
        sv1 += __uint_as_float(cur.x & 0xFFFF0000u);
        sv2 += __uint_as_float(cur.y << 16);
        sv3 += __uint_as_float(cur.y & 0xFFFF0000u);
        cur = nxt;
    }
    sv0 += __uint_as_float(cur.x << 16);
    sv1 += __uint_as_float(cur.x & 0xFFFF0000u);
    sv2 += __uint_as_float(cur.y << 16);
    sv3 += __uint_as_float(cur.y & 0xFFFF0000u);

    const float rd = rden[m];
    float* op = out + (size_t)(bat * T_ + q32 * 32 + m) * 64 + h0;
    f32x4 r;
    r[0] = sv0 * rd; r[1] = sv1 * rd; r[2] = sv2 * rd; r[3] = sv3 * rd;
    *(f32x4*)op = r;
}

// ---------------------------------------------------------------------------
extern "C" void kernel_launch(void* const* d_in, const int* in_sizes, int n_in,
                              void* d_out, int out_size, void* d_ws, size_t ws_size,
                              hipStream_t stream)
{
    const float* x  = (const float*)d_in[0];
    const float* Wk = (const float*)d_in[1];
    const float* Wq = (const float*)d_in[2];
    const float* Wv = (const float*)d_in[3];
    float* out = (float*)d_out;

    u16* ws  = (u16*)d_ws;
    u16* WTf = ws;                          // 98304 u16 (padded to 131072)
    u16* Qf  = ws + 131072;                 // 1048576 u16 each
    u16* Kf  = Qf + 1048576;
    u16* Vf  = Kf + 1048576;
    u32*   pnum = (u32*)(Vf + 1048576);     // 4*SBAT*1024 u32 (layout offsets kept)
    float* pden = (float*)(pnum + (size_t)4 * 1088 * 1024);   // fixed offset (CH-independent)

    wtrans_kernel<<<48, 256, 0, stream>>>(Wq, Wk, Wv, WTf);
    proj_kernel<<<1024, 256, 0, stream>>>(x, WTf, Qf, Kf, Vf);
    attn_kernel<<<SBAT, 256, 0, stream>>>(Qf, Kf, Vf, pnum, pden, out);
    fin_kernel<<<1024, 256, 0, stream>>>(pnum, pden, out);
}

// Round 8
// 116.825 us; speedup vs baseline: 1.1434x; 1.0075x over previous
//
#include <hip/hip_runtime.h>

typedef unsigned short u16;
typedef unsigned int u32;
typedef unsigned long long u64;
typedef __attribute__((ext_vector_type(8))) short short8;
typedef __attribute__((ext_vector_type(4))) float f32x4;

#define T_ 4096
#define QSCALE 0.18033688f   // (1/8) * log2(e): folded into Q at proj time
#define CH 4                 // key-tiles per chunk
#define SBAT 576             // sum over A of 4*ceil((A+1)/CH)  [CH=4]
#define PSTRIDE 36           // P strip row stride in u16 (72 B: 8B-aligned, bank-uniform)

#if __has_builtin(__builtin_amdgcn_exp2f)
#define EXP2F(x) __builtin_amdgcn_exp2f(x)
#else
#define EXP2F(x) exp2f(x)
#endif

__device__ __forceinline__ u16 f2bf(float f) {
    unsigned u = __float_as_uint(f);
    u += 0x7FFFu + ((u >> 16) & 1u);   // RNE to bf16
    return (u16)(u >> 16);
}

// ---------------------------------------------------------------------------
// Kernel 0: W -> WTf in MFMA-B-fragment-contiguous order.
// ---------------------------------------------------------------------------
__global__ __launch_bounds__(256) void wtrans_kernel(
    const float* __restrict__ Wq, const float* __restrict__ Wk,
    const float* __restrict__ Wv, u16* __restrict__ WTf)
{
    const int tid  = blockIdx.x * 256 + threadIdx.x;   // 48*256 = 12288
    const int frag = tid >> 6;                          // 0..191
    const int lane = tid & 63;
    const int ng   = frag >> 4;
    const int kc   = frag & 15;
    const int m    = ng >> 2;
    const float* W = (m == 0) ? Wq : (m == 1) ? Wk : Wv;
    const int h  = (ng & 3) * 16 + (lane & 15);
    const int c0 = kc * 32 + (lane >> 4) * 8;
    short8 v;
    #pragma unroll
    for (int j = 0; j < 8; ++j)
        v[j] = (short)f2bf(W[(c0 + j) * 64 + h]);
    *(short8*)(WTf + (size_t)frag * 512 + lane * 8) = v;
}

// ---------------------------------------------------------------------------
// Kernel 1: projection. (Unchanged.)
// ---------------------------------------------------------------------------
__global__ __launch_bounds__(256) void proj_kernel(
    const float* __restrict__ x, const u16* __restrict__ WTf,
    u16* __restrict__ Qf, u16* __restrict__ Kf, u16* __restrict__ Vf)
{
    __shared__ u16 xs[16 * 520];
    __shared__ u16 img[3072];   // Q @0, K @1024, V @2048 (u16 units)
    const int t    = threadIdx.x;
    const int lane = t & 63;
    const int w    = t >> 6;
    const int l16  = lane & 15;
    const int quad = lane >> 4;
    const int rowbase = blockIdx.x * 16;
    const int bat  = rowbase >> 12;
    const int tloc = rowbase & 4095;

    #pragma unroll
    for (int it = 0; it < 8; ++it) {
        int f   = t + it * 256;                 // float4 index, coalesced
        int row = f >> 7;
        int c4  = (f & 127) * 4;
        f32x4 a = *(const f32x4*)(x + (size_t)(rowbase + row) * 512 + c4);
        unsigned lo = (unsigned)f2bf(a[0]) | ((unsigned)f2bf(a[1]) << 16);
        unsigned hi = (unsigned)f2bf(a[2]) | ((unsigned)f2bf(a[3]) << 16);
        *(uint2*)(xs + row * 520 + c4) = make_uint2(lo, hi);
    }
    __syncthreads();

    f32x4 acc[3];
    #pragma unroll
    for (int nt = 0; nt < 3; ++nt) acc[nt] = (f32x4){0.f, 0.f, 0.f, 0.f};

    const u16* ab = xs + l16 * 520 + quad * 8;
    const u16* wb = WTf + (size_t)(w * 3 * 16) * 512 + lane * 8;

    #pragma unroll 4
    for (int kc = 0; kc < 16; ++kc) {
        short8 af = *(const short8*)(ab + kc * 32);
        #pragma unroll
        for (int nt = 0; nt < 3; ++nt) {
            short8 bf = *(const short8*)(wb + (size_t)(nt * 16 + kc) * 512);
            acc[nt] = __builtin_amdgcn_mfma_f32_16x16x32_bf16(af, bf, acc[nt], 0, 0, 0);
        }
    }

    // ---- epilogue: scatter into LDS image ----
    #pragma unroll
    for (int nt = 0; nt < 3; ++nt) {
        int ng = w * 3 + nt;
        if (ng < 8) {
            int ng4  = ng & 3;
            float sc = (ng < 4) ? QSCALE : 1.0f;
            u16* ib  = img + ((ng < 4) ? 0 : 1024) + (ng4 >> 1) * 512
                          + ((ng4 & 1) * 2 + (l16 >> 3)) * 128 + (l16 & 7);
            #pragma unroll
            for (int i = 0; i < 4; ++i)
                ib[(quad * 4 + i) * 8] = f2bf(acc[nt][i] * sc);
        } else {
            int nt2  = ng - 8;
            unsigned lo = (unsigned)f2bf(acc[nt][0]) | ((unsigned)f2bf(acc[nt][1]) << 16);
            unsigned hi = (unsigned)f2bf(acc[nt][2]) | ((unsigned)f2bf(acc[nt][3]) << 16);
            *(uint2*)(img + 2048 + nt2 * 256 + (quad >> 1) * 128 + l16 * 8
                          + (quad & 1) * 4) = make_uint2(lo, hi);
        }
    }
    __syncthreads();

    // ---- coalesced copy-out ----
    const int tb   = tloc >> 4;
    const int kt   = tloc >> 7;
    const int ks   = (tloc >> 5) & 3;
    const int half = (tloc >> 4) & 1;
    uint2 vq = *(uint2*)(img + t * 4);
    uint2 vk = *(uint2*)(img + 1024 + t * 4);
    uint2 vv = *(uint2*)(img + 2048 + t * 4);
    *(uint2*)(Qf + (size_t)(bat * 256 + tb) * 1024 + t * 4) = vq;
    *(uint2*)(Kf + (size_t)(bat * 256 + tb) * 1024 + t * 4) = vk;
    const int nt2c = t >> 6;
    *(uint2*)(Vf + (size_t)((bat * 32 + kt) * 4 + ks) * 2048
                 + nt2c * 512 + half * 256 + (t & 63) * 4) = vv;
}

// ---------------------------------------------------------------------------
// Kernel 2: attention — NEW this round: explicit 1-deep software pipeline.
// Per step u (one ks of one key tile): (a) K-load + QK MFMAs; (b) den+PV
// MFMAs for step u-1 (ap_prev from strip-read issued last step, av_prev
// loaded last step -> DS/L2 latency hidden under (a)); (c) exp/pack ->
// strip write (parity double-buffer); (d) issue strip read + V loads for
// the NEXT step's (b). Drain after the last body. Accumulation order per
// acc[g][nt2] is unchanged -> bit-identical output vs round 7.
// Barrier-free, direct L2 K/V reads, 4 blocks/CU (LDS 18.4 KB).
// ---------------------------------------------------------------------------
__global__ __launch_bounds__(256, 4) void attn_kernel(
    const u16* __restrict__ Qf, const u16* __restrict__ Kf,
    const u16* __restrict__ Vf, u32* __restrict__ pnum,
    float* __restrict__ pden, float* __restrict__ out)
{
    __shared__ u16 Ps[4][2][2][16 * PSTRIDE];   // [wave][par][g][q*PSTRIDE+s], 18.4 KB

    const int w    = threadIdx.x >> 6;
    const int lane = threadIdx.x & 63;
    const int l16  = lane & 15;
    const int qd   = lane >> 4;
    const int xcd  = blockIdx.x & 7;
    const int bat  = xcd >> 1;
    const int tw   = ((blockIdx.x >> 3) * 2 + (xcd & 1)) * 4 + w;  // 0..SBAT-1

    int A = 31, pre = 0, cc = 1;
    for (;;) {                               // big-A first
        cc = (A + CH) / CH;
        int cnt4 = 4 * cc;
        if (tw < pre + cnt4) break;
        pre += cnt4; --A;
    }
    const int r    = tw - pre;
    const int c    = r >> 2;                 // my chunk (shared by 4 waves)
    const int b_   = r & 3;
    const int nkt  = A + 1;
    const int q32  = 4 * A + b_;
    const int kt0  = c * CH;
    const int kt1  = min(kt0 + CH, nkt);
    const int slot = bat * SBAT + pre + b_ + 4 * c;   // chunk stride 4

    short8 aq[2][2];
    #pragma unroll
    for (int g = 0; g < 2; ++g)
        #pragma unroll
        for (int f = 0; f < 2; ++f)
            aq[g][f] = *(const short8*)(Qf
                + ((size_t)((bat * 256 + q32 * 2 + g) * 2 + f)) * 512 + lane * 8);

    // constant-ones A-fragment for the den MFMA (bf16 1.0 = 0x3F80)
    short8 ones;
    #pragma unroll
    for (int j = 0; j < 8; ++j) ones[j] = (short)0x3F80;

    f32x4 acc[2][4];
    f32x4 accden[2];
    #pragma unroll
    for (int g = 0; g < 2; ++g) {
        accden[g] = (f32x4){0.f, 0.f, 0.f, 0.f};
        for (int n = 0; n < 4; ++n) acc[g][n] = (f32x4){0.f, 0.f, 0.f, 0.f};
    }

    u16* Psw = &Ps[w][0][0][0];    // per-wave base; par offset = par*1152, g offset = g*576
    int par = 0;

    // pipeline registers (consumed one step after they are produced)
    short8 ap_prev[2];
    short8 av_prev[4];

    auto step = [&](int kt, int ks, bool first) __attribute__((always_inline)) {
        const u16* kfb = Kf + ((size_t)(bat * 256 + kt * 8) * 2) * 512 + lane * 8;
        const u16* vfb = Vf + ((size_t)((bat * 32 + kt) * 16)) * 512 + lane * 8;
        // ---- (a) K loads + QK MFMAs -> st regs ----
        f32x4 st0g0, st0g1, st1g0, st1g1;
        {
            short8 k0 = *(const short8*)(kfb + (size_t)(2 * ks) * 1024);
            short8 k1 = *(const short8*)(kfb + (size_t)(2 * ks) * 1024 + 512);
            f32x4 s;
            s = (f32x4){0.f, 0.f, 0.f, 0.f};
            s = __builtin_amdgcn_mfma_f32_16x16x32_bf16(k0, aq[0][0], s, 0, 0, 0);
            s = __builtin_amdgcn_mfma_f32_16x16x32_bf16(k1, aq[0][1], s, 0, 0, 0);
            st0g0 = s;
            s = (f32x4){0.f, 0.f, 0.f, 0.f};
            s = __builtin_amdgcn_mfma_f32_16x16x32_bf16(k0, aq[1][0], s, 0, 0, 0);
            s = __builtin_amdgcn_mfma_f32_16x16x32_bf16(k1, aq[1][1], s, 0, 0, 0);
            st0g1 = s;
        }
        {
            short8 k0 = *(const short8*)(kfb + (size_t)(2 * ks + 1) * 1024);
            short8 k1 = *(const short8*)(kfb + (size_t)(2 * ks + 1) * 1024 + 512);
            f32x4 s;
            s = (f32x4){0.f, 0.f, 0.f, 0.f};
            s = __builtin_amdgcn_mfma_f32_16x16x32_bf16(k0, aq[0][0], s, 0, 0, 0);
            s = __builtin_amdgcn_mfma_f32_16x16x32_bf16(k1, aq[0][1], s, 0, 0, 0);
            st1g0 = s;
            s = (f32x4){0.f, 0.f, 0.f, 0.f};
            s = __builtin_amdgcn_mfma_f32_16x16x32_bf16(k0, aq[1][0], s, 0, 0, 0);
            s = __builtin_amdgcn_mfma_f32_16x16x32_bf16(k1, aq[1][1], s, 0, 0, 0);
            st1g1 = s;
        }
        // ---- (b) den + PV MFMAs for the PREVIOUS step (latency hidden) ----
        if (!first) {
            accden[0] = __builtin_amdgcn_mfma_f32_16x16x32_bf16(ones, ap_prev[0], accden[0], 0, 0, 0);
            accden[1] = __builtin_amdgcn_mfma_f32_16x16x32_bf16(ones, ap_prev[1], accden[1], 0, 0, 0);
            #pragma unroll
            for (int nt2 = 0; nt2 < 4; ++nt2) {
                acc[0][nt2] = __builtin_amdgcn_mfma_f32_16x16x32_bf16(av_prev[nt2], ap_prev[0], acc[0][nt2], 0, 0, 0);
                acc[1][nt2] = __builtin_amdgcn_mfma_f32_16x16x32_bf16(av_prev[nt2], ap_prev[1], acc[1][nt2], 0, 0, 0);
            }
        }
        // ---- (c) exp -> pack -> strip write (parity par) ----
        u16* sw = Psw + par * 1152;
        #pragma unroll
        for (int b = 0; b < 2; ++b) {
            #pragma unroll
            for (int g = 0; g < 2; ++g) {
                f32x4 s = (b == 0) ? (g == 0 ? st0g0 : st0g1)
                                   : (g == 0 ? st1g0 : st1g1);
                float p0 = EXP2F(s[0]);
                float p1 = EXP2F(s[1]);
                float p2 = EXP2F(s[2]);
                float p3 = EXP2F(s[3]);
                u32 q01 = __builtin_amdgcn_perm(__float_as_uint(p1), __float_as_uint(p0), 0x07060302u);
                u32 q23 = __builtin_amdgcn_perm(__float_as_uint(p3), __float_as_uint(p2), 0x07060302u);
                u64 pv = (u64)q01 | ((u64)q23 << 32);
                *(u64*)(sw + g * 576 + l16 * PSTRIDE + b * 16 + qd * 4) = pv;
            }
        }
        // ---- (d) issue next-step consumables: V loads + strip reads ----
        #pragma unroll
        for (int nt2 = 0; nt2 < 4; ++nt2)
            av_prev[nt2] = *(const short8*)(vfb + (size_t)(ks * 4 + nt2) * 512);
        ap_prev[0] = *(const short8*)(sw + 0 * 576 + l16 * PSTRIDE + qd * 8);
        ap_prev[1] = *(const short8*)(sw + 1 * 576 + l16 * PSTRIDE + qd * 8);
        par ^= 1;
    };

    auto body = [&](int kt, bool firstb) __attribute__((always_inline)) {
        step(kt, 0, firstb);
        step(kt, 1, false);
        step(kt, 2, false);
        step(kt, 3, false);
    };

    // straight-line the <=4 key-tile iterations (no dynamic loop)
    body(kt0, true);
    if (kt0 + 1 < kt1) body(kt0 + 1, false);
    if (kt0 + 2 < kt1) body(kt0 + 2, false);
    if (kt0 + 3 < kt1) body(kt0 + 3, false);

    // ---- drain: PV for the final step ----
    accden[0] = __builtin_amdgcn_mfma_f32_16x16x32_bf16(ones, ap_prev[0], accden[0], 0, 0, 0);
    accden[1] = __builtin_amdgcn_mfma_f32_16x16x32_bf16(ones, ap_prev[1], accden[1], 0, 0, 0);
    #pragma unroll
    for (int nt2 = 0; nt2 < 4; ++nt2) {
        acc[0][nt2] = __builtin_amdgcn_mfma_f32_16x16x32_bf16(av_prev[nt2], ap_prev[0], acc[0][nt2], 0, 0, 0);
        acc[1][nt2] = __builtin_amdgcn_mfma_f32_16x16x32_bf16(av_prev[nt2], ap_prev[1], acc[1][nt2], 0, 0, 0);
    }

    // den is replicated across rows by the ones-MFMA: lane-local, no reduce
    float den[2] = { accden[0][0], accden[1][0] };

    if (cc == 1) {
        // single chunk: finalize directly (sole writer of these rows)
        const float rd0 = 1.0f / den[0];
        const float rd1 = 1.0f / den[1];
        float* op = out + ((size_t)(bat * T_ + q32 * 32 + l16)) * 64 + qd * 4;
        #pragma unroll
        for (int g = 0; g < 2; ++g) {
            const float rd = g ? rd1 : rd0;
            #pragma unroll
            for (int nt2 = 0; nt2 < 4; ++nt2) {
                f32x4 v;
                #pragma unroll
                for (int i = 0; i < 4; ++i) v[i] = acc[g][nt2][i] * rd;
                *(f32x4*)(op + (size_t)g * 16 * 64 + nt2 * 16) = v;
            }
        }
    } else {
        // flush: dense nt u64 stores to deterministic slot
        u32* np = pnum + (size_t)slot * 1024;
        #pragma unroll
        for (int g = 0; g < 2; ++g)
            #pragma unroll
            for (int nt2 = 0; nt2 < 4; ++nt2) {
                u32 lo = (u32)f2bf(acc[g][nt2][0]) | ((u32)f2bf(acc[g][nt2][1]) << 16);
                u32 hi = (u32)f2bf(acc[g][nt2][2]) | ((u32)f2bf(acc[g][nt2][3]) << 16);
                u64 val = (u64)lo | ((u64)hi << 32);
                __builtin_nontemporal_store(val, (u64*)(np + (g * 4 + nt2) * 128 + lane * 2));
            }
        if (lane < 32)
            __builtin_nontemporal_store(den[lane >> 4],
                                        &pden[(size_t)slot * 32 + lane]);
    }
}

// ---------------------------------------------------------------------------
// Kernel 3: finalize (round-3 reworked version; adapts to CH via macros).
// ---------------------------------------------------------------------------
__global__ __launch_bounds__(256) void fin_kernel(
    const u32* __restrict__ pnum, const float* __restrict__ pden,
    float* __restrict__ out)
{
    __shared__ float sden[8][32];
    __shared__ float rden[32];
    const int blk  = blockIdx.x;           // 0..1023
    const int xcd  = blk & 7;
    const int bat  = xcd >> 1;
    const int rest = blk >> 3;             // 0..127
    const int q32  = (rest & 63) * 2 + (xcd & 1);
    const int hh   = rest >> 6;            // h half: 0 -> h 0..31, 1 -> 32..63
    const int A = q32 >> 2, b = q32 & 3;
    const int cc = (A + CH) / CH;
    if (cc == 1) return;                   // written directly by attn
    int pre = 0;
    for (int j = 31; j > A; --j) pre += 4 * ((j + CH) / CH);
    const int base = bat * SBAT + pre + b;   // chunk ci at base + 4*ci

    // ---- parallel denominator: 8 groups, ci strided by 8 ----
    {
        const int md  = threadIdx.x & 31;
        const int grp = threadIdx.x >> 5;
        float d = 0.f;
        for (int ci = grp; ci < cc; ci += 8)
            d += pden[(size_t)(base + 4 * ci) * 32 + md];
        sden[grp][md] = d;
    }
    __syncthreads();
    if (threadIdx.x < 32) {
        float d = 0.f;
        #pragma unroll
        for (int g2 = 0; g2 < 8; ++g2) d += sden[g2][threadIdx.x];
        rden[threadIdx.x] = 1.0f / d;
    }
    __syncthreads();

    const int m   = threadIdx.x >> 3;       // out row 0..31
    const int g   = m >> 4;
    const int l16 = m & 15;
    const int h0  = hh * 32 + (threadIdx.x & 7) * 4;   // 4 h per thread
    const int nt2 = h0 >> 4;
    const int q0  = (h0 >> 2) & 3;
    const int off = (g * 4 + nt2) * 128 + q0 * 32 + l16 * 2;

    float sv0 = 0.f, sv1 = 0.f, sv2 = 0.f, sv3 = 0.f;
    const u32* sp = pnum + (size_t)base * 1024 + off;
    uint2 cur = *(const uint2*)sp;
    for (int ci = 1; ci < cc; ++ci) {
        uint2 nxt = *(const uint2*)(sp + (size_t)ci * 4096);   // next in flight
        sv0 += __uint_as_float(cur.x << 16);
        sv1 += __uint_as_float(cur.x & 0xFFFF0000u);
        sv2 += __uint_as_float(cur.y << 16);
        sv3 += __uint_as_float(cur.y & 0xFFFF0000u);
        cur = nxt;
    }
    sv0 += __uint_as_float(cur.x << 16);
    sv1 += __uint_as_float(cur.x & 0xFFFF0000u);
    sv2 += __uint_as_float(cur.y << 16);
    sv3 += __uint_as_float(cur.y & 0xFFFF0000u);

    const float rd = rden[m];
    float* op = out + (size_t)(bat * T_ + q32 * 32 + m) * 64 + h0;
    f32x4 r;
    r[0] = sv0 * rd; r[1] = sv1 * rd; r[2] = sv2 * rd; r[3] = sv3 * rd;
    *(f32x4*)op = r;
}

// ---------------------------------------------------------------------------
extern "C" void kernel_launch(void* const* d_in, const int* in_sizes, int n_in,
                              void* d_out, int out_size, void* d_ws, size_t ws_size,
                              hipStream_t stream)
{
    const float* x  = (const float*)d_in[0];
    const float* Wk = (const float*)d_in[1];
    const float* Wq = (const float*)d_in[2];
    const float* Wv = (const float*)d_in[3];
    float* out = (float*)d_out;

    u16* ws  = (u16*)d_ws;
    u16* WTf = ws;                          // 98304 u16 (padded to 131072)
    u16* Qf  = ws + 131072;                 // 1048576 u16 each
    u16* Kf  = Qf + 1048576;
    u16* Vf  = Kf + 1048576;
    u32*   pnum = (u32*)(Vf + 1048576);     // partial O (layout offsets kept)
    float* pden = (float*)(pnum + (size_t)4 * 1088 * 1024);   // fixed offset (CH-independent)

    wtrans_kernel<<<48, 256, 0, stream>>>(Wq, Wk, Wv, WTf);
    proj_kernel<<<1024, 256, 0, stream>>>(x, WTf, Qf, Kf, Vf);
    attn_kernel<<<SBAT, 256, 0, stream>>>(Qf, Kf, Vf, pnum, pden, out);
    fin_kernel<<<1024, 256, 0, stream>>>(pnum, pden, out);
}

// Round 9
// 114.548 us; speedup vs baseline: 1.1662x; 1.0199x over previous
//
#include <hip/hip_runtime.h>

typedef unsigned short u16;
typedef unsigned int u32;
typedef unsigned long long u64;
typedef __attribute__((ext_vector_type(8))) short short8;
typedef __attribute__((ext_vector_type(4))) float f32x4;

#define T_ 4096
#define QSCALE 0.18033688f   // (1/8) * log2(e): folded into Q at proj time
#define CH 4                 // key-tiles per chunk
#define SBAT 576             // CH=4 slot count per bat (pnum/pden layout, fin-compatible)
#define SGRID 288            // attn grid: 2 waves per chunk (2 q32 per wave)
#define PSTRIDE 36           // P strip row stride in u16 (72 B: 8B-aligned, bank-uniform)

#if __has_builtin(__builtin_amdgcn_exp2f)
#define EXP2F(x) __builtin_amdgcn_exp2f(x)
#else
#define EXP2F(x) exp2f(x)
#endif

__device__ __forceinline__ u16 f2bf(float f) {
    unsigned u = __float_as_uint(f);
    u += 0x7FFFu + ((u >> 16) & 1u);   // RNE to bf16
    return (u16)(u >> 16);
}

// ---------------------------------------------------------------------------
// Kernel 0: W -> WTf in MFMA-B-fragment-contiguous order.
// ---------------------------------------------------------------------------
__global__ __launch_bounds__(256) void wtrans_kernel(
    const float* __restrict__ Wq, const float* __restrict__ Wk,
    const float* __restrict__ Wv, u16* __restrict__ WTf)
{
    const int tid  = blockIdx.x * 256 + threadIdx.x;   // 48*256 = 12288
    const int frag = tid >> 6;                          // 0..191
    const int lane = tid & 63;
    const int ng   = frag >> 4;
    const int kc   = frag & 15;
    const int m    = ng >> 2;
    const float* W = (m == 0) ? Wq : (m == 1) ? Wk : Wv;
    const int h  = (ng & 3) * 16 + (lane & 15);
    const int c0 = kc * 32 + (lane >> 4) * 8;
    short8 v;
    #pragma unroll
    for (int j = 0; j < 8; ++j)
        v[j] = (short)f2bf(W[(c0 + j) * 64 + h]);
    *(short8*)(WTf + (size_t)frag * 512 + lane * 8) = v;
}

// ---------------------------------------------------------------------------
// Kernel 1: projection. (Unchanged.)
// ---------------------------------------------------------------------------
__global__ __launch_bounds__(256) void proj_kernel(
    const float* __restrict__ x, const u16* __restrict__ WTf,
    u16* __restrict__ Qf, u16* __restrict__ Kf, u16* __restrict__ Vf)
{
    __shared__ u16 xs[16 * 520];
    __shared__ u16 img[3072];   // Q @0, K @1024, V @2048 (u16 units)
    const int t    = threadIdx.x;
    const int lane = t & 63;
    const int w    = t >> 6;
    const int l16  = lane & 15;
    const int quad = lane >> 4;
    const int rowbase = blockIdx.x * 16;
    const int bat  = rowbase >> 12;
    const int tloc = rowbase & 4095;

    #pragma unroll
    for (int it = 0; it < 8; ++it) {
        int f   = t + it * 256;                 // float4 index, coalesced
        int row = f >> 7;
        int c4  = (f & 127) * 4;
        f32x4 a = *(const f32x4*)(x + (size_t)(rowbase + row) * 512 + c4);
        unsigned lo = (unsigned)f2bf(a[0]) | ((unsigned)f2bf(a[1]) << 16);
        unsigned hi = (unsigned)f2bf(a[2]) | ((unsigned)f2bf(a[3]) << 16);
        *(uint2*)(xs + row * 520 + c4) = make_uint2(lo, hi);
    }
    __syncthreads();

    f32x4 acc[3];
    #pragma unroll
    for (int nt = 0; nt < 3; ++nt) acc[nt] = (f32x4){0.f, 0.f, 0.f, 0.f};

    const u16* ab = xs + l16 * 520 + quad * 8;
    const u16* wb = WTf + (size_t)(w * 3 * 16) * 512 + lane * 8;

    #pragma unroll 4
    for (int kc = 0; kc < 16; ++kc) {
        short8 af = *(const short8*)(ab + kc * 32);
        #pragma unroll
        for (int nt = 0; nt < 3; ++nt) {
            short8 bf = *(const short8*)(wb + (size_t)(nt * 16 + kc) * 512);
            acc[nt] = __builtin_amdgcn_mfma_f32_16x16x32_bf16(af, bf, acc[nt], 0, 0, 0);
        }
    }

    // ---- epilogue: scatter into LDS image ----
    #pragma unroll
    for (int nt = 0; nt < 3; ++nt) {
        int ng = w * 3 + nt;
        if (ng < 8) {
            int ng4  = ng & 3;
            float sc = (ng < 4) ? QSCALE : 1.0f;
            u16* ib  = img + ((ng < 4) ? 0 : 1024) + (ng4 >> 1) * 512
                          + ((ng4 & 1) * 2 + (l16 >> 3)) * 128 + (l16 & 7);
            #pragma unroll
            for (int i = 0; i < 4; ++i)
                ib[(quad * 4 + i) * 8] = f2bf(acc[nt][i] * sc);
        } else {
            int nt2  = ng - 8;
            unsigned lo = (unsigned)f2bf(acc[nt][0]) | ((unsigned)f2bf(acc[nt][1]) << 16);
            unsigned hi = (unsigned)f2bf(acc[nt][2]) | ((unsigned)f2bf(acc[nt][3]) << 16);
            *(uint2*)(img + 2048 + nt2 * 256 + (quad >> 1) * 128 + l16 * 8
                          + (quad & 1) * 4) = make_uint2(lo, hi);
        }
    }
    __syncthreads();

    // ---- coalesced copy-out ----
    const int tb   = tloc >> 4;
    const int kt   = tloc >> 7;
    const int ks   = (tloc >> 5) & 3;
    const int half = (tloc >> 4) & 1;
    uint2 vq = *(uint2*)(img + t * 4);
    uint2 vk = *(uint2*)(img + 1024 + t * 4);
    uint2 vv = *(uint2*)(img + 2048 + t * 4);
    *(uint2*)(Qf + (size_t)(bat * 256 + tb) * 1024 + t * 4) = vq;
    *(uint2*)(Kf + (size_t)(bat * 256 + tb) * 1024 + t * 4) = vk;
    const int nt2c = t >> 6;
    *(uint2*)(Vf + (size_t)((bat * 32 + kt) * 4 + ks) * 2048
                 + nt2c * 512 + half * 256 + (t & 63) * 4) = vv;
}

// ---------------------------------------------------------------------------
// Kernel 2: attention — NEW this round: one wave owns TWO q32 groups
// (64 q-rows = 4 g-fragments). Every K/V fragment now feeds 4 QK / 4 PV
// MFMAs instead of 2 -> per-wave K/V bytes per unit work HALVE (the L1-BW
// binder per the r6/r8 post-mortems). 2 waves per chunk (bp = pair index);
// grid 288 blocks, all-resident at 2 blocks/CU (launch_bounds(256,2),
// VGPR ~220). Keeps r8's 1-deep software pipeline (ap/av prev) and the
// CH=4 pnum/pden slot layout (slot_j = bat*576 + 2*pre2 + 2*bp + j + 4*c)
// so fin is unchanged. Per-acc MFMA order identical -> bit-identical out.
// ---------------------------------------------------------------------------
__global__ __launch_bounds__(256, 2) void attn_kernel(
    const u16* __restrict__ Qf, const u16* __restrict__ Kf,
    const u16* __restrict__ Vf, u32* __restrict__ pnum,
    float* __restrict__ pden, float* __restrict__ out)
{
    __shared__ u16 Ps[4][2][4][16 * PSTRIDE];   // [wave][par][gg][...], 36.9 KB

    const int w    = threadIdx.x >> 6;
    const int lane = threadIdx.x & 63;
    const int l16  = lane & 15;
    const int qd   = lane >> 4;
    const int xcd  = blockIdx.x & 7;
    const int bat  = xcd >> 1;
    const int tw   = ((blockIdx.x >> 3) * 2 + (xcd & 1)) * 4 + w;  // 0..SGRID-1

    int A = 31, pre = 0, cc = 1;
    for (;;) {                               // big-A first; pre counts 2 tasks/chunk
        cc = (A + CH) / CH;
        int cnt2 = 2 * cc;
        if (tw < pre + cnt2) break;
        pre += cnt2; --A;
    }
    const int r    = tw - pre;
    const int c    = r >> 1;                 // my chunk (shared by 2 waves)
    const int bp   = r & 1;                  // q32-pair index: q32 = 4A+2bp+{0,1}
    const int nkt  = A + 1;
    const int q32a = 4 * A + 2 * bp;
    const int kt0  = c * CH;
    const int kt1  = min(kt0 + CH, nkt);
    // r8-compatible CH=4 slot numbering (pre4 = 2*pre2):
    const int slot0 = bat * SBAT + 2 * pre + 2 * bp + 4 * c;   // j=0; j=1 at +1

    short8 aq[4][2];                         // gg = j*2 + g
    #pragma unroll
    for (int gg = 0; gg < 4; ++gg)
        #pragma unroll
        for (int f = 0; f < 2; ++f)
            aq[gg][f] = *(const short8*)(Qf
                + ((size_t)((bat * 256 + (q32a + (gg >> 1)) * 2 + (gg & 1)) * 2 + f)) * 512 + lane * 8);

    // constant-ones A-fragment for the den MFMA (bf16 1.0 = 0x3F80)
    short8 ones;
    #pragma unroll
    for (int j = 0; j < 8; ++j) ones[j] = (short)0x3F80;

    f32x4 acc[4][4];
    f32x4 accden[4];
    #pragma unroll
    for (int gg = 0; gg < 4; ++gg) {
        accden[gg] = (f32x4){0.f, 0.f, 0.f, 0.f};
        #pragma unroll
        for (int n = 0; n < 4; ++n) acc[gg][n] = (f32x4){0.f, 0.f, 0.f, 0.f};
    }

    u16* Psw = &Ps[w][0][0][0];    // par stride 2304 u16, gg stride 576
    int par = 0;

    // pipeline registers (consumed one step after they are produced)
    short8 ap_prev[4];
    short8 av_prev[4];

    auto step = [&](int kt, int ks, bool first) __attribute__((always_inline)) {
        const u16* kfb = Kf + ((size_t)(bat * 256 + kt * 8) * 2) * 512 + lane * 8;
        const u16* vfb = Vf + ((size_t)((bat * 32 + kt) * 16)) * 512 + lane * 8;
        // ---- (a) K loads + QK MFMAs -> st regs (each K frag feeds 4 gg) ----
        f32x4 st[2][4];
        #pragma unroll
        for (int b = 0; b < 2; ++b) {
            short8 k0 = *(const short8*)(kfb + (size_t)(2 * ks + b) * 1024);
            short8 k1 = *(const short8*)(kfb + (size_t)(2 * ks + b) * 1024 + 512);
            #pragma unroll
            for (int gg = 0; gg < 4; ++gg) {
                f32x4 s = (f32x4){0.f, 0.f, 0.f, 0.f};
                s = __builtin_amdgcn_mfma_f32_16x16x32_bf16(k0, aq[gg][0], s, 0, 0, 0);
                s = __builtin_amdgcn_mfma_f32_16x16x32_bf16(k1, aq[gg][1], s, 0, 0, 0);
                st[b][gg] = s;
            }
        }
        // ---- (b) den + PV MFMAs for the PREVIOUS step (latency hidden) ----
        if (!first) {
            #pragma unroll
            for (int gg = 0; gg < 4; ++gg)
                accden[gg] = __builtin_amdgcn_mfma_f32_16x16x32_bf16(ones, ap_prev[gg], accden[gg], 0, 0, 0);
            #pragma unroll
            for (int nt2 = 0; nt2 < 4; ++nt2)
                #pragma unroll
                for (int gg = 0; gg < 4; ++gg)
                    acc[gg][nt2] = __builtin_amdgcn_mfma_f32_16x16x32_bf16(av_prev[nt2], ap_prev[gg], acc[gg][nt2], 0, 0, 0);
        }
        // ---- (c) exp -> pack -> strip write (parity par) ----
        u16* sw = Psw + par * 2304;
        #pragma unroll
        for (int b = 0; b < 2; ++b) {
            #pragma unroll
            for (int gg = 0; gg < 4; ++gg) {
                f32x4 s = st[b][gg];
                float p0 = EXP2F(s[0]);
                float p1 = EXP2F(s[1]);
                float p2 = EXP2F(s[2]);
                float p3 = EXP2F(s[3]);
                u32 q01 = __builtin_amdgcn_perm(__float_as_uint(p1), __float_as_uint(p0), 0x07060302u);
                u32 q23 = __builtin_amdgcn_perm(__float_as_uint(p3), __float_as_uint(p2), 0x07060302u);
                u64 pv = (u64)q01 | ((u64)q23 << 32);
                *(u64*)(sw + gg * 576 + l16 * PSTRIDE + b * 16 + qd * 4) = pv;
            }
        }
        // ---- (d) issue next-step consumables: V loads + strip reads ----
        #pragma unroll
        for (int nt2 = 0; nt2 < 4; ++nt2)
            av_prev[nt2] = *(const short8*)(vfb + (size_t)(ks * 4 + nt2) * 512);
        #pragma unroll
        for (int gg = 0; gg < 4; ++gg)
            ap_prev[gg] = *(const short8*)(sw + gg * 576 + l16 * PSTRIDE + qd * 8);
        par ^= 1;
    };

    auto body = [&](int kt, bool firstb) __attribute__((always_inline)) {
        step(kt, 0, firstb);
        step(kt, 1, false);
        step(kt, 2, false);
        step(kt, 3, false);
    };

    // straight-line the <=4 key-tile iterations (no dynamic loop)
    body(kt0, true);
    if (kt0 + 1 < kt1) body(kt0 + 1, false);
    if (kt0 + 2 < kt1) body(kt0 + 2, false);
    if (kt0 + 3 < kt1) body(kt0 + 3, false);

    // ---- drain: den + PV for the final step ----
    #pragma unroll
    for (int gg = 0; gg < 4; ++gg)
        accden[gg] = __builtin_amdgcn_mfma_f32_16x16x32_bf16(ones, ap_prev[gg], accden[gg], 0, 0, 0);
    #pragma unroll
    for (int nt2 = 0; nt2 < 4; ++nt2)
        #pragma unroll
        for (int gg = 0; gg < 4; ++gg)
            acc[gg][nt2] = __builtin_amdgcn_mfma_f32_16x16x32_bf16(av_prev[nt2], ap_prev[gg], acc[gg][nt2], 0, 0, 0);

    // den is replicated across rows by the ones-MFMA: lane-local, no reduce
    float den[4] = { accden[0][0], accden[1][0], accden[2][0], accden[3][0] };

    if (cc == 1) {
        // single chunk: finalize both q32 groups directly (sole writer)
        #pragma unroll
        for (int j = 0; j < 2; ++j) {
            float* op = out + ((size_t)(bat * T_ + (q32a + j) * 32 + l16)) * 64 + qd * 4;
            #pragma unroll
            for (int g = 0; g < 2; ++g) {
                const float rd = 1.0f / den[j * 2 + g];
                #pragma unroll
                for (int nt2 = 0; nt2 < 4; ++nt2) {
                    f32x4 v;
                    #pragma unroll
                    for (int i = 0; i < 4; ++i) v[i] = acc[j * 2 + g][nt2][i] * rd;
                    *(f32x4*)(op + (size_t)g * 16 * 64 + nt2 * 16) = v;
                }
            }
        }
    } else {
        // flush: dense nt u64 stores to both deterministic slots
        #pragma unroll
        for (int j = 0; j < 2; ++j) {
            u32* np = pnum + (size_t)(slot0 + j) * 1024;
            #pragma unroll
            for (int g = 0; g < 2; ++g)
                #pragma unroll
                for (int nt2 = 0; nt2 < 4; ++nt2) {
                    u32 lo = (u32)f2bf(acc[j * 2 + g][nt2][0]) | ((u32)f2bf(acc[j * 2 + g][nt2][1]) << 16);
                    u32 hi = (u32)f2bf(acc[j * 2 + g][nt2][2]) | ((u32)f2bf(acc[j * 2 + g][nt2][3]) << 16);
                    u64 val = (u64)lo | ((u64)hi << 32);
                    __builtin_nontemporal_store(val, (u64*)(np + (g * 4 + nt2) * 128 + lane * 2));
                }
        }
        if (lane < 32) {
            __builtin_nontemporal_store(den[lane >> 4],
                                        &pden[(size_t)slot0 * 32 + lane]);
            __builtin_nontemporal_store(den[2 + (lane >> 4)],
                                        &pden[(size_t)(slot0 + 1) * 32 + lane]);
        }
    }
}

// ---------------------------------------------------------------------------
// Kernel 3: finalize (r8 version, unchanged — slot layout is r8-compatible).
// ---------------------------------------------------------------------------
__global__ __launch_bounds__(256) void fin_kernel(
    const u32* __restrict__ pnum, const float* __restrict__ pden,
    float* __restrict__ out)
{
    __shared__ float sden[8][32];
    __shared__ float rden[32];
    const int blk  = blockIdx.x;           // 0..1023
    const int xcd  = blk & 7;
    const int bat  = xcd >> 1;
    const int rest = blk >> 3;             // 0..127
    const int q32  = (rest & 63) * 2 + (xcd & 1);
    const int hh   = rest >> 6;            // h half: 0 -> h 0..31, 1 -> 32..63
    const int A = q32 >> 2, b = q32 & 3;
    const int cc = (A + CH) / CH;
    if (cc == 1) return;                   // written directly by attn
    int pre = 0;
    for (int j = 31; j > A; --j) pre += 4 * ((j + CH) / CH);
    const int base = bat * SBAT + pre + b;   // chunk ci at base + 4*ci

    // ---- parallel denominator: 8 groups, ci strided by 8 ----
    {
        const int md  = threadIdx.x & 31;
        const int grp = threadIdx.x >> 5;
        float d = 0.f;
        for (int ci = grp; ci < cc; ci += 8)
            d += pden[(size_t)(base + 4 * ci) * 32 + md];
        sden[grp][md] = d;
    }
    __syncthreads();
    if (threadIdx.x < 32) {
        float d = 0.f;
        #pragma unroll
        for (int g2 = 0; g2 < 8; ++g2) d += sden[g2][threadIdx.x];
        rden[threadIdx.x] = 1.0f / d;
    }
    __syncthreads();

    const int m   = threadIdx.x >> 3;       // out row 0..31
    const int g   = m >> 4;
    const int l16 = m & 15;
    const int h0  = hh * 32 + (threadIdx.x & 7) * 4;   // 4 h per thread
    const int nt2 = h0 >> 4;
    const int q0  = (h0 >> 2) & 3;
    const int off = (g * 4 + nt2) * 128 + q0 * 32 + l16 * 2;

    float sv0 = 0.f, sv1 = 0.f, sv2 = 0.f, sv3 = 0.f;
    const u32* sp = pnum + (size_t)base * 1024 + off;
    uint2 cur = *(const uint2*)sp;
    for (int ci = 1; ci < cc; ++ci) {
        uint2 nxt = *(const uint2*)(sp + (size_t)ci * 4096);   // next in flight
        sv0 += __uint_as_float(cur.x << 16);
        sv1 += __uint_as_float(cur.x & 0xFFFF0000u);
        sv2 += __uint_as_float(cur.y << 16);
        sv3 += __uint_as_float(cur.y & 0xFFFF0000u);
        cur = nxt;
    }
    sv0 += __uint_as_float(cur.x << 16);
    sv1 += __uint_as_float(cur.x & 0xFFFF0000u);
    sv2 += __uint_as_float(cur.y << 16);
    sv3 += __uint_as_float(cur.y & 0xFFFF0000u);

    const float rd = rden[m];
    float* op = out + (size_t)(bat * T_ + q32 * 32 + m) * 64 + h0;
    f32x4 r;
    r[0] = sv0 * rd; r[1] = sv1 * rd; r[2] = sv2 * rd; r[3] = sv3 * rd;
    *(f32x4*)op = r;
}

// ---------------------------------------------------------------------------
extern "C" void kernel_launch(void* const* d_in, const int* in_sizes, int n_in,
                              void* d_out, int out_size, void* d_ws, size_t ws_size,
                              hipStream_t stream)
{
    const float* x  = (const float*)d_in[0];
    const float* Wk = (const float*)d_in[1];
    const float* Wq = (const float*)d_in[2];
    const float* Wv = (const float*)d_in[3];
    float* out = (float*)d_out;

    u16* ws  = (u16*)d_ws;
    u16* WTf = ws;                          // 98304 u16 (padded to 131072)
    u16* Qf  = ws + 131072;                 // 1048576 u16 each
    u16* Kf  = Qf + 1048576;
    u16* Vf  = Kf + 1048576;
    u32*   pnum = (u32*)(Vf + 1048576);     // partial O (layout offsets kept)
    float* pden = (float*)(pnum + (size_t)4 * 1088 * 1024);   // fixed offset (CH-independent)

    wtrans_kernel<<<48, 256, 0, stream>>>(Wq, Wk, Wv, WTf);
    proj_kernel<<<1024, 256, 0, stream>>>(x, WTf, Qf, Kf, Vf);
    attn_kernel<<<SGRID, 256, 0, stream>>>(Qf, Kf, Vf, pnum, pden, out);
    fin_kernel<<<1024, 256, 0, stream>>>(pnum, pden, out);
}